// Round 7
// baseline (157.428 us; speedup 1.0000x reference)
//
#include <hip/hip_runtime.h>
#include <hip/hip_fp16.h>

#define NFEAT 128
#define NBUK_MAX 1024   // actual buckets = ceil(50000/64) = 782
#define HB 256          // blocks for hist/scatter passes
#define BCAP_L 4096     // per-bucket LDS edge capacity (mean 2046, sigma ~45)

// ---------- Wt[k][j] = W[j][k] (64 KB) ----------
__global__ void k_transpose(const float* __restrict__ W, float* __restrict__ Wt) {
    int i = blockIdx.x * 256 + threadIdx.x;
    if (i < NFEAT * NFEAT) {
        int r = i >> 7, c = i & 127;
        Wt[c * NFEAT + r] = W[i];
    }
}

// ---------- z(fp16) = h @ W^T, s1 = z.w1, s2 = z.w2 (scores from fp32 acc) ----------
__global__ __launch_bounds__(256) void k_gemm(
    const float* __restrict__ h, const float* __restrict__ Wt,
    const float* __restrict__ attn_w,
    __half* __restrict__ zh, float* __restrict__ s1, float* __restrict__ s2, int n)
{
    __shared__ float hs[32][NFEAT];
    const int tid = threadIdx.x;
    const int cg = tid & 31;
    const int rg = tid >> 5;
    const int nodeBase = blockIdx.x * 32;

    const float4* h4 = reinterpret_cast<const float4*>(h);
    float4* hs4 = reinterpret_cast<float4*>(&hs[0][0]);
    for (int t = tid; t < 32 * 32; t += 256) {
        int row = t >> 5, c4 = t & 31;
        int nn = nodeBase + row;
        hs4[t] = (nn < n) ? h4[(size_t)nn * 32 + c4] : make_float4(0.f, 0.f, 0.f, 0.f);
    }
    __syncthreads();

    const float4* Wt4 = reinterpret_cast<const float4*>(Wt);
    float acc[4][4];
#pragma unroll
    for (int r = 0; r < 4; ++r)
#pragma unroll
        for (int c = 0; c < 4; ++c) acc[r][c] = 0.f;

    for (int k0 = 0; k0 < NFEAT; k0 += 4) {
        float4 wv[4];
#pragma unroll
        for (int i = 0; i < 4; ++i) wv[i] = Wt4[(size_t)(k0 + i) * 32 + cg];
        float4 hv[4];
#pragma unroll
        for (int r = 0; r < 4; ++r)
            hv[r] = *reinterpret_cast<const float4*>(&hs[rg * 4 + r][k0]);
#pragma unroll
        for (int r = 0; r < 4; ++r) {
            float hk;
#pragma unroll
            for (int i = 0; i < 4; ++i) {
                hk = (i == 0) ? hv[r].x : (i == 1) ? hv[r].y : (i == 2) ? hv[r].z : hv[r].w;
                acc[r][0] += hk * wv[i].x;
                acc[r][1] += hk * wv[i].y;
                acc[r][2] += hk * wv[i].z;
                acc[r][3] += hk * wv[i].w;
            }
        }
    }

    const float4 aw1 = reinterpret_cast<const float4*>(attn_w)[cg];
    const float4 aw2 = reinterpret_cast<const float4*>(attn_w)[cg + 32];
    uint2* zh2 = reinterpret_cast<uint2*>(zh);

#pragma unroll
    for (int r = 0; r < 4; ++r) {
        int node = nodeBase + rg * 4 + r;
        bool valid = node < n;
        if (valid) {
            __half2 a01 = __floats2half2_rn(acc[r][0], acc[r][1]);
            __half2 a23 = __floats2half2_rn(acc[r][2], acc[r][3]);
            uint2 pk;
            pk.x = *reinterpret_cast<unsigned*>(&a01);
            pk.y = *reinterpret_cast<unsigned*>(&a23);
            zh2[(size_t)node * 32 + cg] = pk;
        }
        float p1 = acc[r][0] * aw1.x + acc[r][1] * aw1.y + acc[r][2] * aw1.z + acc[r][3] * aw1.w;
        float p2 = acc[r][0] * aw2.x + acc[r][1] * aw2.y + acc[r][2] * aw2.z + acc[r][3] * aw2.w;
#pragma unroll
        for (int off = 16; off > 0; off >>= 1) {
            p1 += __shfl_xor(p1, off);
            p2 += __shfl_xor(p2, off);
        }
        if (cg == 0 && valid) { s1[node] = p1; s2[node] = p2; }
    }
}

// ---------- pass 1: per-block LDS histogram over coarse buckets ----------
__global__ __launch_bounds__(256) void k_hist(const int* __restrict__ dst,
                                              int* __restrict__ hist,
                                              int e, int nbuk, int epb)
{
    __shared__ int lh[NBUK_MAX];
    const int b = blockIdx.x, tid = threadIdx.x;
    for (int k = tid; k < nbuk; k += 256) lh[k] = 0;
    __syncthreads();
    const int beg = b * epb, end = min(e, beg + epb);
    for (int i = beg + tid; i < end; i += 256)
        atomicAdd(&lh[dst[i] >> 6], 1);
    __syncthreads();
    for (int k = tid; k < nbuk; k += 256)
        hist[b * nbuk + k] = lh[k];
}

// ---------- pass 2a: per-bucket exclusive scan over blocks ----------
__global__ __launch_bounds__(256) void k_scan_blocks(const int* __restrict__ hist,
                                                     int* __restrict__ base,
                                                     int* __restrict__ bucket_tot, int nbuk)
{
    __shared__ int wsum[4];
    const int k = blockIdx.x, tid = threadIdx.x;
    int v = hist[tid * nbuk + k];
    int lane = tid & 63, wave = tid >> 6;
    int x = v;
#pragma unroll
    for (int off = 1; off < 64; off <<= 1) {
        int t = __shfl_up(x, off);
        if (lane >= off) x += t;
    }
    if (lane == 63) wsum[wave] = x;
    __syncthreads();
    int wb = 0;
    for (int w = 0; w < wave; ++w) wb += wsum[w];
    base[tid * nbuk + k] = wb + x - v;
    if (tid == 255) bucket_tot[k] = wb + x;
}

// ---------- pass 2b: exclusive scan of bucket totals (single block) ----------
__global__ __launch_bounds__(256) void k_scan_buckets(const int* __restrict__ bucket_tot,
                                                      int* __restrict__ bucket_base, int nbuk)
{
    __shared__ int wsum[4];
    const int tid = threadIdx.x;
    const int C = (nbuk + 255) / 256;   // <= 4
    const int base_i = tid * C;
    int vals[8];
    int s = 0;
#pragma unroll
    for (int j = 0; j < 8; ++j) {
        int v = 0;
        if (j < C) {
            int idx = base_i + j;
            if (idx < nbuk) v = bucket_tot[idx];
        }
        vals[j] = v; s += v;
    }
    int lane = tid & 63, wave = tid >> 6;
    int x = s;
#pragma unroll
    for (int off = 1; off < 64; off <<= 1) {
        int t = __shfl_up(x, off);
        if (lane >= off) x += t;
    }
    if (lane == 63) wsum[wave] = x;
    __syncthreads();
    int wb = 0;
    for (int w = 0; w < wave; ++w) wb += wsum[w];
    int ex = wb + x - s;
#pragma unroll
    for (int j = 0; j < 8; ++j) {
        if (j < C) {
            int idx = base_i + j;
            if (idx < nbuk) bucket_base[idx] = ex;
            ex += vals[j];
        }
    }
}

// ---------- pass 3: deterministic scatter into coarse-sorted store ----------
// packed word: (dst&63)<<22 | etype<<16 | src
__global__ __launch_bounds__(256) void k_sctr(
    const int* __restrict__ src, const int* __restrict__ dst, const int* __restrict__ etype,
    const int* __restrict__ base, const int* __restrict__ bucket_base,
    unsigned int* __restrict__ bucket_store, int e, int nbuk, int epb)
{
    __shared__ int cur[NBUK_MAX];
    const int b = blockIdx.x, tid = threadIdx.x;
    for (int k = tid; k < nbuk; k += 256)
        cur[k] = base[b * nbuk + k] + bucket_base[k];
    __syncthreads();
    const int beg = b * epb, end = min(e, beg + epb);
    for (int i = beg + tid; i < end; i += 256) {
        int d = dst[i];
        int pos = atomicAdd(&cur[d >> 6], 1);
        bucket_store[pos] =
            (unsigned int)src[i] | ((unsigned int)etype[i] << 16) | ((unsigned int)(d & 63) << 22);
    }
}

// ---------- fused: per-bucket LDS sort + softmax + weighted aggregation ----------
// one block per 64-node bucket; 4 waves x 16 nodes each; edge metadata in LDS.
__global__ __launch_bounds__(256) void k_agg_bucket(
    const __half* __restrict__ zh, const float* __restrict__ s1, const float* __restrict__ s2,
    const float* __restrict__ rel_emb, const float* __restrict__ bias,
    const unsigned int* __restrict__ bucket_store, const int* __restrict__ bucket_tot,
    const int* __restrict__ bucket_base,
    float* __restrict__ out, int n)
{
    __shared__ unsigned int est[BCAP_L];
    __shared__ unsigned int srt[BCAP_L];
    __shared__ int cnt64[64];
    __shared__ int lofs[65];
    __shared__ int curs[64];

    const int b = blockIdx.x;
    const int tid = threadIdx.x;
    const int wv = tid >> 6, lane = tid & 63;
    const int cnt = min(bucket_tot[b], BCAP_L);
    const int gbase = bucket_base[b];

    if (tid < 64) cnt64[tid] = 0;
    __syncthreads();
    for (int j = tid; j < cnt; j += 256) {
        unsigned int pk = bucket_store[(size_t)gbase + j];
        est[j] = pk;
        atomicAdd(&cnt64[pk >> 22], 1);
    }
    __syncthreads();
    if (tid < 64) {   // wave 0: exclusive scan of 64 node counts
        int v = cnt64[tid];
        int x = v;
#pragma unroll
        for (int off = 1; off < 64; off <<= 1) {
            int t = __shfl_up(x, off);
            if (tid >= off) x += t;
        }
        lofs[tid] = x - v;
        curs[tid] = x - v;
        if (tid == 63) lofs[64] = x;
    }
    __syncthreads();
    for (int j = tid; j < cnt; j += 256) {
        unsigned int pk = est[j];
        int pos = atomicAdd(&curs[pk >> 22], 1);
        srt[pos] = pk;
    }
    __syncthreads();

    const int quad = lane >> 4;   // which edge of the group of 4
    const int q    = lane & 15;   // 8-half chunk within the 128-feat row
    const uint4* z4 = reinterpret_cast<const uint4*>(zh);
    const float4* b4 = reinterpret_cast<const float4*>(bias);
    const float4 bv0 = b4[q * 2], bv1 = b4[q * 2 + 1];
    float4* o4 = reinterpret_cast<float4*>(out);

    for (int i = 0; i < 16; ++i) {
        const int nl = wv * 16 + i;
        const int node = (b << 6) + nl;
        if (node >= n) break;
        const int lbeg = lofs[nl];
        const int lend = lofs[nl + 1];
        const int deg = lend - lbeg;

        float acc[8];
#pragma unroll
        for (int j = 0; j < 8; ++j) acc[j] = 0.f;

        if (deg > 0) {
            const float s2n = s2[node];
            // phase 1: exact max
            float mymax = -3.4e38f;
            for (int k = lbeg + lane; k < lend; k += 64) {
                unsigned int pk = srt[k];
                float ev = s1[pk & 0xFFFFu] + s2n;
                ev = ev > 0.f ? ev : 0.01f * ev;
                mymax = fmaxf(mymax, ev);
            }
#pragma unroll
            for (int off = 32; off > 0; off >>= 1)
                mymax = fmaxf(mymax, __shfl_xor(mymax, off));
            // phase 2: denominator
            float den = 0.f;
            for (int k = lbeg + lane; k < lend; k += 64) {
                unsigned int pk = srt[k];
                float ev = s1[pk & 0xFFFFu] + s2n;
                ev = ev > 0.f ? ev : 0.01f * ev;
                den += __expf(ev - mymax);
            }
#pragma unroll
            for (int off = 32; off > 0; off >>= 1)
                den += __shfl_xor(den, off);
            const float inv = 1.f / den;

            // phase 3: gather, chunks of 64 edges
            for (int cb = lbeg; cb < lend; cb += 64) {
                const int cc = min(64, lend - cb);
                int   src_i = 0;
                float wgt   = 0.f;
                if (lane < cc) {
                    unsigned int pk = srt[cb + lane];
                    int s = pk & 0xFFFFu;
                    float ev = s1[s] + s2n;
                    ev = ev > 0.f ? ev : 0.01f * ev;
                    src_i = s;
                    wgt = rel_emb[(pk >> 16) & 0x3Fu] * __expf(ev - mymax) * inv;
                }
                int jb = 0;
                for (; jb + 16 <= cc; jb += 16) {
                    const int j0 = jb + quad;
                    int   sA = __shfl(src_i, j0),      sB = __shfl(src_i, j0 + 4);
                    int   sC = __shfl(src_i, j0 + 8),  sD = __shfl(src_i, j0 + 12);
                    float wA = __shfl(wgt, j0),        wB = __shfl(wgt, j0 + 4);
                    float wC = __shfl(wgt, j0 + 8),    wD = __shfl(wgt, j0 + 12);
                    uint4 vA = z4[(size_t)sA * 16 + q];
                    uint4 vB = z4[(size_t)sB * 16 + q];
                    uint4 vC = z4[(size_t)sC * 16 + q];
                    uint4 vD = z4[(size_t)sD * 16 + q];
                    const __half* hA = reinterpret_cast<const __half*>(&vA);
                    const __half* hB = reinterpret_cast<const __half*>(&vB);
                    const __half* hC = reinterpret_cast<const __half*>(&vC);
                    const __half* hD = reinterpret_cast<const __half*>(&vD);
#pragma unroll
                    for (int k2 = 0; k2 < 8; ++k2) {
                        acc[k2] += wA * __half2float(hA[k2]);
                        acc[k2] += wB * __half2float(hB[k2]);
                        acc[k2] += wC * __half2float(hC[k2]);
                        acc[k2] += wD * __half2float(hD[k2]);
                    }
                }
                for (; jb < cc; jb += 4) {
                    const int j = jb + quad;   // j < 64 always; wgt=0 beyond cc
                    int   sj = __shfl(src_i, j);
                    float wj = __shfl(wgt, j);
                    uint4 zv = z4[(size_t)sj * 16 + q];
                    const __half* hp = reinterpret_cast<const __half*>(&zv);
#pragma unroll
                    for (int k2 = 0; k2 < 8; ++k2)
                        acc[k2] += wj * __half2float(hp[k2]);
                }
            }
            // reduce across the 4 quads
#pragma unroll
            for (int j = 0; j < 8; ++j) {
                acc[j] += __shfl_xor(acc[j], 16);
                acc[j] += __shfl_xor(acc[j], 32);
            }
        }

        if (quad == 0) {
            o4[(size_t)node * 32 + q * 2] =
                make_float4(acc[0] + bv0.x, acc[1] + bv0.y, acc[2] + bv0.z, acc[3] + bv0.w);
            o4[(size_t)node * 32 + q * 2 + 1] =
                make_float4(acc[4] + bv1.x, acc[5] + bv1.y, acc[6] + bv1.z, acc[7] + bv1.w);
        }
    }
}

extern "C" void kernel_launch(void* const* d_in, const int* in_sizes, int n_in,
                              void* d_out, int out_size, void* d_ws, size_t ws_size,
                              hipStream_t stream) {
    const float* h      = (const float*)d_in[0];
    const float* W      = (const float*)d_in[1];
    const float* attn_w = (const float*)d_in[2];
    const float* rel    = (const float*)d_in[3];
    const float* bias   = (const float*)d_in[4];
    const int*   src    = (const int*)d_in[5];
    const int*   dst    = (const int*)d_in[6];
    const int*   etype  = (const int*)d_in[7];
    const int n = in_sizes[0] / NFEAT;   // 50000
    const int e = in_sizes[5];           // 1600000
    const int nbuk = (n + 63) / 64;      // 782
    const int epb = (e + HB - 1) / HB;   // 6250
    float* out = (float*)d_out;

    // workspace layout
    char* p = (char*)d_ws;
    __half* zh = (__half*)p;               p += (size_t)n * NFEAT * 2;
    float* s1 = (float*)p;                 p += (size_t)n * 4;
    float* s2 = (float*)p;                 p += (size_t)n * 4;
    float* Wt = (float*)p;                 p += (size_t)NFEAT * NFEAT * 4;
    int* hist       = (int*)p;             p += (size_t)HB * nbuk * 4;
    int* base       = (int*)p;             p += (size_t)HB * nbuk * 4;
    int* bucket_tot = (int*)p;             p += (size_t)nbuk * 4;
    int* bucket_base= (int*)p;             p += (size_t)nbuk * 4;
    unsigned int* bucket_store = (unsigned int*)p;  p += (size_t)e * 4;

    k_transpose<<<(NFEAT * NFEAT + 255) / 256, 256, 0, stream>>>(W, Wt);
    k_gemm<<<(n + 31) / 32, 256, 0, stream>>>(h, Wt, attn_w, zh, s1, s2, n);
    k_hist<<<HB, 256, 0, stream>>>(dst, hist, e, nbuk, epb);
    k_scan_blocks<<<nbuk, 256, 0, stream>>>(hist, base, bucket_tot, nbuk);
    k_scan_buckets<<<1, 256, 0, stream>>>(bucket_tot, bucket_base, nbuk);
    k_sctr<<<HB, 256, 0, stream>>>(src, dst, etype, base, bucket_base, bucket_store, e, nbuk, epb);
    k_agg_bucket<<<nbuk, 256, 0, stream>>>(zh, s1, s2, rel, bias,
                                           bucket_store, bucket_tot, bucket_base, out, n);
}

// Round 8
// 128.730 us; speedup vs baseline: 1.2229x; 1.2229x over previous
//
#include <hip/hip_runtime.h>
#include <hip/hip_fp16.h>

#define NFEAT 128
#define NBUK_MAX 1024   // actual buckets = ceil(50000/64) = 782
#define HB 256          // blocks for hist/scatter passes
#define BCAP_L 4096     // k_place LDS edge capacity (mean 2046, sigma ~45)
#define HPAD 136        // padded LDS row stride in halves (272 B -> 4-bank rotate)

typedef __attribute__((ext_vector_type(8))) _Float16 f16x8;
typedef __attribute__((ext_vector_type(4))) float f32x4;

// ---------- MFMA gemm: z(fp16) = h @ W^T, s1 = z.w1, s2 = z.w2 ----------
// 64 nodes/block, 4 waves x 16 nodes. B[k][n] = W[n][k] -> read W rows directly.
__global__ __launch_bounds__(256) void k_gemm_mfma(
    const float* __restrict__ h, const float* __restrict__ W,
    const float* __restrict__ attn_w,
    __half* __restrict__ zh, float* __restrict__ s1, float* __restrict__ s2, int n)
{
    __shared__ _Float16 hsh[64 * HPAD];    // h tile; later reused per-wave as z staging
    __shared__ _Float16 wsh[128 * HPAD];   // W (out x in) in fp16
    const int tid = threadIdx.x;
    const int wv = tid >> 6, lane = tid & 63;
    const int nodeBase = blockIdx.x * 64;

    {   // stage W: 128x128 fp32 -> fp16
        const float4* W4 = reinterpret_cast<const float4*>(W);
        for (int t = tid; t < 128 * 32; t += 256) {
            int r = t >> 5, c4 = t & 31;
            float4 v = W4[t];
            _Float16* d = &wsh[r * HPAD + c4 * 4];
            d[0] = (_Float16)v.x; d[1] = (_Float16)v.y;
            d[2] = (_Float16)v.z; d[3] = (_Float16)v.w;
        }
    }
    {   // stage h tile: 64x128 fp32 -> fp16
        const float4* h4 = reinterpret_cast<const float4*>(h);
        for (int t = tid; t < 64 * 32; t += 256) {
            int r = t >> 5, c4 = t & 31;
            int node = nodeBase + r;
            float4 v = (node < n) ? h4[(size_t)node * 32 + c4]
                                  : make_float4(0.f, 0.f, 0.f, 0.f);
            _Float16* d = &hsh[r * HPAD + c4 * 4];
            d[0] = (_Float16)v.x; d[1] = (_Float16)v.y;
            d[2] = (_Float16)v.z; d[3] = (_Float16)v.w;
        }
    }
    __syncthreads();

    const int arow = lane & 15;   // A-row / B-col / C-col
    const int kgrp = lane >> 4;   // k-group 0..3
    f32x4 acc[8];
#pragma unroll
    for (int t = 0; t < 8; ++t) acc[t] = (f32x4){0.f, 0.f, 0.f, 0.f};

#pragma unroll
    for (int k0 = 0; k0 < 128; k0 += 32) {
        f16x8 a = *reinterpret_cast<const f16x8*>(
            &hsh[(wv * 16 + arow) * HPAD + k0 + kgrp * 8]);
#pragma unroll
        for (int nt = 0; nt < 8; ++nt) {
            f16x8 b = *reinterpret_cast<const f16x8*>(
                &wsh[(nt * 16 + arow) * HPAD + k0 + kgrp * 8]);
            acc[nt] = __builtin_amdgcn_mfma_f32_16x16x32_f16(a, b, acc[nt], 0, 0, 0);
        }
    }

    // s1/s2 from fp32 accumulators: lane holds cols nt*16+arow, rows kgrp*4+r
    {
        float pr1[4] = {0.f, 0.f, 0.f, 0.f}, pr2[4] = {0.f, 0.f, 0.f, 0.f};
#pragma unroll
        for (int nt = 0; nt < 8; ++nt) {
            float w1v = attn_w[nt * 16 + arow];
            float w2v = attn_w[128 + nt * 16 + arow];
#pragma unroll
            for (int r = 0; r < 4; ++r) {
                pr1[r] += acc[nt][r] * w1v;
                pr2[r] += acc[nt][r] * w2v;
            }
        }
#pragma unroll
        for (int off = 1; off < 16; off <<= 1) {
#pragma unroll
            for (int r = 0; r < 4; ++r) {
                pr1[r] += __shfl_xor(pr1[r], off);
                pr2[r] += __shfl_xor(pr2[r], off);
            }
        }
        if (arow == 0) {
#pragma unroll
            for (int r = 0; r < 4; ++r) {
                int node = nodeBase + wv * 16 + kgrp * 4 + r;
                if (node < n) { s1[node] = pr1[r]; s2[node] = pr2[r]; }
            }
        }
    }

    // stage z frags into wave-private LDS (alias of this wave's h rows), then
    // write coalesced: lane -> row (arow), 64B chunk (kgrp)
    _Float16* zout = &hsh[wv * 16 * HPAD];
#pragma unroll
    for (int nt = 0; nt < 8; ++nt)
#pragma unroll
        for (int r = 0; r < 4; ++r)
            zout[(kgrp * 4 + r) * HPAD + nt * 16 + arow] = (_Float16)acc[nt][r];

    {
        int node = nodeBase + wv * 16 + arow;
        if (node < n) {
            const uint4* zsrc = reinterpret_cast<const uint4*>(&zout[arow * HPAD + kgrp * 32]);
            uint4* zdst = reinterpret_cast<uint4*>(zh) + (size_t)node * 16 + kgrp * 4;
            uint4 v0 = zsrc[0], v1 = zsrc[1], v2 = zsrc[2], v3 = zsrc[3];
            zdst[0] = v0; zdst[1] = v1; zdst[2] = v2; zdst[3] = v3;
        }
    }
}

// ---------- pass 1: per-block LDS histogram over coarse buckets ----------
__global__ __launch_bounds__(256) void k_hist(const int* __restrict__ dst,
                                              int* __restrict__ hist,
                                              int e, int nbuk, int epb)
{
    __shared__ int lh[NBUK_MAX];
    const int b = blockIdx.x, tid = threadIdx.x;
    for (int k = tid; k < nbuk; k += 256) lh[k] = 0;
    __syncthreads();
    const int beg = b * epb, end = min(e, beg + epb);
    for (int i = beg + tid; i < end; i += 256)
        atomicAdd(&lh[dst[i] >> 6], 1);
    __syncthreads();
    for (int k = tid; k < nbuk; k += 256)
        hist[b * nbuk + k] = lh[k];
}

// ---------- pass 2a: per-bucket exclusive scan over blocks ----------
__global__ __launch_bounds__(256) void k_scan_blocks(const int* __restrict__ hist,
                                                     int* __restrict__ base,
                                                     int* __restrict__ bucket_tot, int nbuk)
{
    __shared__ int wsum[4];
    const int k = blockIdx.x, tid = threadIdx.x;
    int v = hist[tid * nbuk + k];
    int lane = tid & 63, wave = tid >> 6;
    int x = v;
#pragma unroll
    for (int off = 1; off < 64; off <<= 1) {
        int t = __shfl_up(x, off);
        if (lane >= off) x += t;
    }
    if (lane == 63) wsum[wave] = x;
    __syncthreads();
    int wb = 0;
    for (int w = 0; w < wave; ++w) wb += wsum[w];
    base[tid * nbuk + k] = wb + x - v;
    if (tid == 255) bucket_tot[k] = wb + x;
}

// ---------- pass 2b: exclusive scan of bucket totals (single block) ----------
__global__ __launch_bounds__(256) void k_scan_buckets(const int* __restrict__ bucket_tot,
                                                      int* __restrict__ bucket_base,
                                                      int* __restrict__ row_start,
                                                      int n, int nbuk)
{
    __shared__ int wsum[4];
    const int tid = threadIdx.x;
    const int C = (nbuk + 255) / 256;   // <= 4
    const int base_i = tid * C;
    int vals[8];
    int s = 0;
#pragma unroll
    for (int j = 0; j < 8; ++j) {
        int v = 0;
        if (j < C) {
            int idx = base_i + j;
            if (idx < nbuk) v = bucket_tot[idx];
        }
        vals[j] = v; s += v;
    }
    int lane = tid & 63, wave = tid >> 6;
    int x = s;
#pragma unroll
    for (int off = 1; off < 64; off <<= 1) {
        int t = __shfl_up(x, off);
        if (lane >= off) x += t;
    }
    if (lane == 63) wsum[wave] = x;
    __syncthreads();
    int wb = 0;
    for (int w = 0; w < wave; ++w) wb += wsum[w];
    int ex = wb + x - s;
#pragma unroll
    for (int j = 0; j < 8; ++j) {
        if (j < C) {
            int idx = base_i + j;
            if (idx < nbuk) bucket_base[idx] = ex;
            ex += vals[j];
        }
    }
    if (tid == 255) row_start[n] = ex;   // == e
}

// ---------- pass 3: deterministic scatter into coarse-sorted store ----------
// packed word: (dst&63)<<22 | etype<<16 | src
__global__ __launch_bounds__(256) void k_sctr(
    const int* __restrict__ src, const int* __restrict__ dst, const int* __restrict__ etype,
    const int* __restrict__ base, const int* __restrict__ bucket_base,
    unsigned int* __restrict__ bucket_store, int e, int nbuk, int epb)
{
    __shared__ int cur[NBUK_MAX];
    const int b = blockIdx.x, tid = threadIdx.x;
    for (int k = tid; k < nbuk; k += 256)
        cur[k] = base[b * nbuk + k] + bucket_base[k];
    __syncthreads();
    const int beg = b * epb, end = min(e, beg + epb);
    for (int i = beg + tid; i < end; i += 256) {
        int d = dst[i];
        int pos = atomicAdd(&cur[d >> 6], 1);
        bucket_store[pos] =
            (unsigned int)src[i] | ((unsigned int)etype[i] << 16) | ((unsigned int)(d & 63) << 22);
    }
}

// ---------- pass 4: per-bucket local sort -> CSR + row_start ----------
__global__ __launch_bounds__(256) void k_place(
    const unsigned int* __restrict__ bucket_store, const int* __restrict__ bucket_tot,
    const int* __restrict__ bucket_base,
    int* __restrict__ row_start, unsigned int* __restrict__ edge_list, int n)
{
    __shared__ unsigned int est[BCAP_L];
    __shared__ int cnt64[64];
    const int b = blockIdx.x;
    const int tid = threadIdx.x;
    const int cnt = min(bucket_tot[b], BCAP_L);
    const int base = bucket_base[b];

    if (tid < 64) cnt64[tid] = 0;
    for (int j = tid; j < cnt; j += 256)
        est[j] = bucket_store[(size_t)base + j];
    __syncthreads();
    for (int j = tid; j < cnt; j += 256)
        atomicAdd(&cnt64[est[j] >> 22], 1);
    __syncthreads();
    if (tid < 64) {
        int v = cnt64[tid];
        int x = v;
#pragma unroll
        for (int off = 1; off < 64; off <<= 1) {
            int t = __shfl_up(x, off);
            if (tid >= off) x += t;
        }
        int node = (b << 6) + tid;
        if (node < n) row_start[node] = base + x - v;
        cnt64[tid] = x - v;
    }
    __syncthreads();
    for (int j = tid; j < cnt; j += 256) {
        unsigned int pk = est[j];
        int pos = base + atomicAdd(&cnt64[pk >> 22], 1);
        edge_list[pos] = pk & 0x3FFFFFu;
    }
}

// ---------- per-node softmax + weighted aggregation; 1 wave = 1 node ----------
__global__ __launch_bounds__(256) void k_aggregate(
    const __half* __restrict__ zh, const float* __restrict__ s1, const float* __restrict__ s2,
    const float* __restrict__ rel_emb, const float* __restrict__ bias,
    const int* __restrict__ row_start, const unsigned int* __restrict__ edge_list,
    float* __restrict__ out, int n)
{
    __shared__ uint2 lds_ws[4][64];   // rare path only
    const int wv   = threadIdx.x >> 6;
    const int lane = threadIdx.x & 63;
    const int node = blockIdx.x * 4 + wv;
    if (node >= n) return;

    const int beg = row_start[node];
    const int end = row_start[node + 1];
    const int deg = end - beg;
    const int quad = lane >> 4;
    const int q    = lane & 15;

    float acc[8];
#pragma unroll
    for (int j = 0; j < 8; ++j) acc[j] = 0.f;
    const uint4* z4 = reinterpret_cast<const uint4*>(zh);

    if (deg > 0) {
        const float s2n = s2[node];

        if (deg <= 64) {
            unsigned int pk = 0;
            float ev = -3.4e38f;
            const bool has = lane < deg;
            if (has) {
                pk = edge_list[beg + lane];
                ev = s1[pk & 0xFFFFu] + s2n;
                ev = ev > 0.f ? ev : 0.01f * ev;
            }
            float m = ev;
#pragma unroll
            for (int off = 32; off > 0; off >>= 1)
                m = fmaxf(m, __shfl_xor(m, off));
            float p = has ? __expf(ev - m) : 0.f;
            float den = p;
#pragma unroll
            for (int off = 32; off > 0; off >>= 1)
                den += __shfl_xor(den, off);
            const float inv = 1.f / den;
            const int   src_i = has ? (int)(pk & 0xFFFFu) : 0;
            const float wgt   = has ? rel_emb[pk >> 16] * p * inv : 0.f;

            int jb = 0;
            for (; jb + 16 <= deg; jb += 16) {
                const int j0 = jb + quad;
                int   sA = __shfl(src_i, j0),      sB = __shfl(src_i, j0 + 4);
                int   sC = __shfl(src_i, j0 + 8),  sD = __shfl(src_i, j0 + 12);
                float wA = __shfl(wgt, j0),        wB = __shfl(wgt, j0 + 4);
                float wC = __shfl(wgt, j0 + 8),    wD = __shfl(wgt, j0 + 12);
                uint4 vA = z4[(size_t)sA * 16 + q];
                uint4 vB = z4[(size_t)sB * 16 + q];
                uint4 vC = z4[(size_t)sC * 16 + q];
                uint4 vD = z4[(size_t)sD * 16 + q];
                const __half* hA = reinterpret_cast<const __half*>(&vA);
                const __half* hB = reinterpret_cast<const __half*>(&vB);
                const __half* hC = reinterpret_cast<const __half*>(&vC);
                const __half* hD = reinterpret_cast<const __half*>(&vD);
#pragma unroll
                for (int k2 = 0; k2 < 8; ++k2) {
                    acc[k2] += wA * __half2float(hA[k2]);
                    acc[k2] += wB * __half2float(hB[k2]);
                    acc[k2] += wC * __half2float(hC[k2]);
                    acc[k2] += wD * __half2float(hD[k2]);
                }
            }
            for (; jb < deg; jb += 4) {
                const int j = jb + quad;
                int   sj = __shfl(src_i, j);
                float wj = __shfl(wgt, j);
                uint4 zv = z4[(size_t)sj * 16 + q];
                const __half* hp = reinterpret_cast<const __half*>(&zv);
#pragma unroll
                for (int k2 = 0; k2 < 8; ++k2)
                    acc[k2] += wj * __half2float(hp[k2]);
            }
        } else {
            float mymax = -3.4e38f;
            for (int k = beg + lane; k < end; k += 64) {
                unsigned int pk = edge_list[k];
                float ev = s1[pk & 0xFFFFu] + s2n;
                ev = ev > 0.f ? ev : 0.01f * ev;
                mymax = fmaxf(mymax, ev);
            }
#pragma unroll
            for (int off = 32; off > 0; off >>= 1)
                mymax = fmaxf(mymax, __shfl_xor(mymax, off));
            float mysum = 0.f;
            for (int k = beg + lane; k < end; k += 64) {
                unsigned int pk = edge_list[k];
                float ev = s1[pk & 0xFFFFu] + s2n;
                ev = ev > 0.f ? ev : 0.01f * ev;
                mysum += __expf(ev - mymax);
            }
#pragma unroll
            for (int off = 32; off > 0; off >>= 1)
                mysum += __shfl_xor(mysum, off);
            const float inv = 1.f / mysum;

            for (int cb = beg; cb < end; cb += 64) {
                int k = cb + lane;
                if (k < end) {
                    unsigned int pk = edge_list[k];
                    int s = pk & 0xFFFFu;
                    float ev = s1[s] + s2n;
                    ev = ev > 0.f ? ev : 0.01f * ev;
                    lds_ws[wv][lane] = make_uint2((unsigned)s,
                        __float_as_uint(rel_emb[pk >> 16] * __expf(ev - mymax) * inv));
                }
                int cnt = min(64, end - cb);
#pragma unroll 2
                for (int j = quad; j < cnt; j += 4) {
                    uint2 t = lds_ws[wv][j];
                    float w = __uint_as_float(t.y);
                    uint4 zv = z4[(size_t)t.x * 16 + q];
                    const __half* hp = reinterpret_cast<const __half*>(&zv);
#pragma unroll
                    for (int k2 = 0; k2 < 8; ++k2)
                        acc[k2] += w * __half2float(hp[k2]);
                }
            }
        }
#pragma unroll
        for (int j = 0; j < 8; ++j) {
            acc[j] += __shfl_xor(acc[j], 16);
            acc[j] += __shfl_xor(acc[j], 32);
        }
    }

    if (quad == 0) {
        const float4* b4 = reinterpret_cast<const float4*>(bias);
        float4 b0 = b4[q * 2], b1 = b4[q * 2 + 1];
        float4* o4 = reinterpret_cast<float4*>(out);
        o4[(size_t)node * 32 + q * 2] =
            make_float4(acc[0] + b0.x, acc[1] + b0.y, acc[2] + b0.z, acc[3] + b0.w);
        o4[(size_t)node * 32 + q * 2 + 1] =
            make_float4(acc[4] + b1.x, acc[5] + b1.y, acc[6] + b1.z, acc[7] + b1.w);
    }
}

extern "C" void kernel_launch(void* const* d_in, const int* in_sizes, int n_in,
                              void* d_out, int out_size, void* d_ws, size_t ws_size,
                              hipStream_t stream) {
    const float* h      = (const float*)d_in[0];
    const float* W      = (const float*)d_in[1];
    const float* attn_w = (const float*)d_in[2];
    const float* rel    = (const float*)d_in[3];
    const float* bias   = (const float*)d_in[4];
    const int*   src    = (const int*)d_in[5];
    const int*   dst    = (const int*)d_in[6];
    const int*   etype  = (const int*)d_in[7];
    const int n = in_sizes[0] / NFEAT;   // 50000
    const int e = in_sizes[5];           // 1600000
    const int nbuk = (n + 63) / 64;      // 782
    const int epb = (e + HB - 1) / HB;   // 6250
    float* out = (float*)d_out;

    // workspace layout
    char* p = (char*)d_ws;
    __half* zh = (__half*)p;               p += (size_t)n * NFEAT * 2;
    float* s1 = (float*)p;                 p += (size_t)n * 4;
    float* s2 = (float*)p;                 p += (size_t)n * 4;
    int* row_start = (int*)p;              p += (size_t)(n + 1) * 4;
    int* hist       = (int*)p;             p += (size_t)HB * nbuk * 4;
    int* base       = (int*)p;             p += (size_t)HB * nbuk * 4;
    int* bucket_tot = (int*)p;             p += (size_t)nbuk * 4;
    int* bucket_base= (int*)p;             p += (size_t)nbuk * 4;
    unsigned int* edge_list    = (unsigned int*)p;  p += (size_t)e * 4;
    unsigned int* bucket_store = (unsigned int*)p;  p += (size_t)e * 4;

    k_gemm_mfma<<<(n + 63) / 64, 256, 0, stream>>>(h, W, attn_w, zh, s1, s2, n);
    k_hist<<<HB, 256, 0, stream>>>(dst, hist, e, nbuk, epb);
    k_scan_blocks<<<nbuk, 256, 0, stream>>>(hist, base, bucket_tot, nbuk);
    k_scan_buckets<<<1, 256, 0, stream>>>(bucket_tot, bucket_base, row_start, n, nbuk);
    k_sctr<<<HB, 256, 0, stream>>>(src, dst, etype, base, bucket_base, bucket_store, e, nbuk, epb);
    k_place<<<nbuk, 256, 0, stream>>>(bucket_store, bucket_tot, bucket_base, row_start, edge_list, n);
    k_aggregate<<<(n + 3) / 4, 256, 0, stream>>>(zh, s1, s2, rel, bias, row_start, edge_list, out, n);
}

// Round 9
// 124.237 us; speedup vs baseline: 1.2672x; 1.0362x over previous
//
#include <hip/hip_runtime.h>
#include <hip/hip_fp16.h>

#define NFEAT 128
#define NBUK_MAX 1024   // actual buckets = ceil(50000/64) = 782
#define HB 256          // blocks for hist/scatter passes
#define EPB_MAX 6272    // LDS staging capacity per scatter block (epb = 6250)
#define BCAP_L 4096     // k_place LDS edge capacity (mean 2046, sigma ~45)
#define HPAD 136        // padded LDS row stride in halves

typedef __attribute__((ext_vector_type(8))) _Float16 f16x8;
typedef __attribute__((ext_vector_type(4))) float f32x4;

// ---------- MFMA gemm: z(fp16) = h @ W^T, s1 = z.w1, s2 = z.w2 ----------
__global__ __launch_bounds__(256) void k_gemm_mfma(
    const float* __restrict__ h, const float* __restrict__ W,
    const float* __restrict__ attn_w,
    __half* __restrict__ zh, float* __restrict__ s1, float* __restrict__ s2, int n)
{
    __shared__ _Float16 hsh[64 * HPAD];    // h tile; later reused per-wave as z staging
    __shared__ _Float16 wsh[128 * HPAD];   // W (out x in) in fp16
    const int tid = threadIdx.x;
    const int wv = tid >> 6, lane = tid & 63;
    const int nodeBase = blockIdx.x * 64;

    {   // stage W: 128x128 fp32 -> fp16
        const float4* W4 = reinterpret_cast<const float4*>(W);
        for (int t = tid; t < 128 * 32; t += 256) {
            int r = t >> 5, c4 = t & 31;
            float4 v = W4[t];
            _Float16* d = &wsh[r * HPAD + c4 * 4];
            d[0] = (_Float16)v.x; d[1] = (_Float16)v.y;
            d[2] = (_Float16)v.z; d[3] = (_Float16)v.w;
        }
    }
    {   // stage h tile: 64x128 fp32 -> fp16
        const float4* h4 = reinterpret_cast<const float4*>(h);
        for (int t = tid; t < 64 * 32; t += 256) {
            int r = t >> 5, c4 = t & 31;
            int node = nodeBase + r;
            float4 v = (node < n) ? h4[(size_t)node * 32 + c4]
                                  : make_float4(0.f, 0.f, 0.f, 0.f);
            _Float16* d = &hsh[r * HPAD + c4 * 4];
            d[0] = (_Float16)v.x; d[1] = (_Float16)v.y;
            d[2] = (_Float16)v.z; d[3] = (_Float16)v.w;
        }
    }
    __syncthreads();

    const int arow = lane & 15;   // A-row / B-col / C-col
    const int kgrp = lane >> 4;   // k-group 0..3
    f32x4 acc[8];
#pragma unroll
    for (int t = 0; t < 8; ++t) acc[t] = (f32x4){0.f, 0.f, 0.f, 0.f};

#pragma unroll
    for (int k0 = 0; k0 < 128; k0 += 32) {
        f16x8 a = *reinterpret_cast<const f16x8*>(
            &hsh[(wv * 16 + arow) * HPAD + k0 + kgrp * 8]);
#pragma unroll
        for (int nt = 0; nt < 8; ++nt) {
            f16x8 b = *reinterpret_cast<const f16x8*>(
                &wsh[(nt * 16 + arow) * HPAD + k0 + kgrp * 8]);
            acc[nt] = __builtin_amdgcn_mfma_f32_16x16x32_f16(a, b, acc[nt], 0, 0, 0);
        }
    }

    // s1/s2 from fp32 accumulators: lane holds cols nt*16+arow, rows kgrp*4+r
    {
        float pr1[4] = {0.f, 0.f, 0.f, 0.f}, pr2[4] = {0.f, 0.f, 0.f, 0.f};
#pragma unroll
        for (int nt = 0; nt < 8; ++nt) {
            float w1v = attn_w[nt * 16 + arow];
            float w2v = attn_w[128 + nt * 16 + arow];
#pragma unroll
            for (int r = 0; r < 4; ++r) {
                pr1[r] += acc[nt][r] * w1v;
                pr2[r] += acc[nt][r] * w2v;
            }
        }
#pragma unroll
        for (int off = 1; off < 16; off <<= 1) {
#pragma unroll
            for (int r = 0; r < 4; ++r) {
                pr1[r] += __shfl_xor(pr1[r], off);
                pr2[r] += __shfl_xor(pr2[r], off);
            }
        }
        if (arow == 0) {
#pragma unroll
            for (int r = 0; r < 4; ++r) {
                int node = nodeBase + wv * 16 + kgrp * 4 + r;
                if (node < n) { s1[node] = pr1[r]; s2[node] = pr2[r]; }
            }
        }
    }

    _Float16* zout = &hsh[wv * 16 * HPAD];
#pragma unroll
    for (int nt = 0; nt < 8; ++nt)
#pragma unroll
        for (int r = 0; r < 4; ++r)
            zout[(kgrp * 4 + r) * HPAD + nt * 16 + arow] = (_Float16)acc[nt][r];

    {
        int node = nodeBase + wv * 16 + arow;
        if (node < n) {
            const uint4* zsrc = reinterpret_cast<const uint4*>(&zout[arow * HPAD + kgrp * 32]);
            uint4* zdst = reinterpret_cast<uint4*>(zh) + (size_t)node * 16 + kgrp * 4;
            uint4 v0 = zsrc[0], v1 = zsrc[1], v2 = zsrc[2], v3 = zsrc[3];
            zdst[0] = v0; zdst[1] = v1; zdst[2] = v2; zdst[3] = v3;
        }
    }
}

// ---------- pass 1: per-block LDS histogram over coarse buckets ----------
__global__ __launch_bounds__(256) void k_hist(const int* __restrict__ dst,
                                              int* __restrict__ hist,
                                              int e, int nbuk, int epb)
{
    __shared__ int lh[NBUK_MAX];
    const int b = blockIdx.x, tid = threadIdx.x;
    for (int k = tid; k < nbuk; k += 256) lh[k] = 0;
    __syncthreads();
    const int beg = b * epb, end = min(e, beg + epb);
    for (int i = beg + tid; i < end; i += 256)
        atomicAdd(&lh[dst[i] >> 6], 1);
    __syncthreads();
    for (int k = tid; k < nbuk; k += 256)
        hist[b * nbuk + k] = lh[k];
}

// ---------- pass 2a: per-bucket exclusive scan over blocks ----------
__global__ __launch_bounds__(256) void k_scan_blocks(const int* __restrict__ hist,
                                                     int* __restrict__ base,
                                                     int* __restrict__ bucket_tot, int nbuk)
{
    __shared__ int wsum[4];
    const int k = blockIdx.x, tid = threadIdx.x;
    int v = hist[tid * nbuk + k];
    int lane = tid & 63, wave = tid >> 6;
    int x = v;
#pragma unroll
    for (int off = 1; off < 64; off <<= 1) {
        int t = __shfl_up(x, off);
        if (lane >= off) x += t;
    }
    if (lane == 63) wsum[wave] = x;
    __syncthreads();
    int wb = 0;
    for (int w = 0; w < wave; ++w) wb += wsum[w];
    base[tid * nbuk + k] = wb + x - v;
    if (tid == 255) bucket_tot[k] = wb + x;
}

// ---------- pass 2b: exclusive scan of bucket totals (single block) ----------
__global__ __launch_bounds__(256) void k_scan_buckets(const int* __restrict__ bucket_tot,
                                                      int* __restrict__ bucket_base,
                                                      int* __restrict__ row_start,
                                                      int n, int nbuk)
{
    __shared__ int wsum[4];
    const int tid = threadIdx.x;
    const int C = (nbuk + 255) / 256;   // <= 4
    const int base_i = tid * C;
    int vals[8];
    int s = 0;
#pragma unroll
    for (int j = 0; j < 8; ++j) {
        int v = 0;
        if (j < C) {
            int idx = base_i + j;
            if (idx < nbuk) v = bucket_tot[idx];
        }
        vals[j] = v; s += v;
    }
    int lane = tid & 63, wave = tid >> 6;
    int x = s;
#pragma unroll
    for (int off = 1; off < 64; off <<= 1) {
        int t = __shfl_up(x, off);
        if (lane >= off) x += t;
    }
    if (lane == 63) wsum[wave] = x;
    __syncthreads();
    int wb = 0;
    for (int w = 0; w < wave; ++w) wb += wsum[w];
    int ex = wb + x - s;
#pragma unroll
    for (int j = 0; j < 8; ++j) {
        if (j < C) {
            int idx = base_i + j;
            if (idx < nbuk) bucket_base[idx] = ex;
            ex += vals[j];
        }
    }
    if (tid == 255) row_start[n] = ex;   // == e
}

// ---------- pass 3: LDS-staged dense scatter into coarse-sorted store ----------
// packed word: (dst&63)<<22 | etype<<16 | src. Global writes are linear over
// the block's bucket-sorted staging buffer -> dense runs, no write scatter.
__global__ __launch_bounds__(256) void k_sctr(
    const int* __restrict__ src, const int* __restrict__ dst, const int* __restrict__ etype,
    const int* __restrict__ base, const int* __restrict__ bucket_base,
    unsigned int* __restrict__ bucket_store, int e, int nbuk, int epb)
{
    __shared__ unsigned int est[EPB_MAX];
    __shared__ unsigned short bkt[EPB_MAX];
    __shared__ int lcnt[NBUK_MAX];    // counts -> exclusive local offsets
    __shared__ int gbase[NBUK_MAX];   // gpos = gbase[k] + local_index
    __shared__ int lcur[NBUK_MAX];
    __shared__ int wsum[4];

    const int b = blockIdx.x, tid = threadIdx.x;
    const int beg = b * epb, end = min(e, beg + epb);
    const int cnt = end - beg;

    for (int k = tid; k < nbuk; k += 256) lcnt[k] = 0;
    __syncthreads();
    for (int i = beg + tid; i < end; i += 256)
        atomicAdd(&lcnt[dst[i] >> 6], 1);
    __syncthreads();

    // block-local exclusive scan of lcnt[0..nbuk)
    const int C = (nbuk + 255) / 256;   // <= 4
    const int bi = tid * C;
    int vals[4];
    int s = 0;
#pragma unroll
    for (int j = 0; j < 4; ++j) {
        int v = 0;
        if (j < C) {
            int idx = bi + j;
            if (idx < nbuk) v = lcnt[idx];
        }
        vals[j] = v; s += v;
    }
    const int lane = tid & 63, wv = tid >> 6;
    int x = s;
#pragma unroll
    for (int off = 1; off < 64; off <<= 1) {
        int t = __shfl_up(x, off);
        if (lane >= off) x += t;
    }
    if (lane == 63) wsum[wv] = x;
    __syncthreads();
    int wb = 0;
    for (int w = 0; w < wv; ++w) wb += wsum[w];
    int ex = wb + x - s;
#pragma unroll
    for (int j = 0; j < 4; ++j) {
        if (j < C) {
            int idx = bi + j;
            if (idx < nbuk) {
                lcnt[idx] = ex;
                lcur[idx] = ex;
                gbase[idx] = bucket_base[idx] + base[b * nbuk + idx] - ex;
                ex += vals[j];
            }
        }
    }
    __syncthreads();

    // scatter into LDS (bucket-sorted within block)
    for (int i = beg + tid; i < end; i += 256) {
        int d = dst[i];
        int k = d >> 6;
        unsigned int word =
            (unsigned int)src[i] | ((unsigned int)etype[i] << 16) | ((unsigned int)(d & 63) << 22);
        int pos = atomicAdd(&lcur[k], 1);
        est[pos] = word;
        bkt[pos] = (unsigned short)k;
    }
    __syncthreads();

    // linear drain: dense per-run global writes at exact precomputed bases
    for (int j = tid; j < cnt; j += 256)
        bucket_store[gbase[bkt[j]] + j] = est[j];
}

// ---------- pass 4: per-bucket local sort -> CSR + row_start ----------
__global__ __launch_bounds__(256) void k_place(
    const unsigned int* __restrict__ bucket_store, const int* __restrict__ bucket_tot,
    const int* __restrict__ bucket_base,
    int* __restrict__ row_start, unsigned int* __restrict__ edge_list, int n)
{
    __shared__ unsigned int est[BCAP_L];
    __shared__ int cnt64[64];
    const int b = blockIdx.x;
    const int tid = threadIdx.x;
    const int cnt = min(bucket_tot[b], BCAP_L);
    const int base = bucket_base[b];

    if (tid < 64) cnt64[tid] = 0;
    for (int j = tid; j < cnt; j += 256)
        est[j] = bucket_store[(size_t)base + j];
    __syncthreads();
    for (int j = tid; j < cnt; j += 256)
        atomicAdd(&cnt64[est[j] >> 22], 1);
    __syncthreads();
    if (tid < 64) {
        int v = cnt64[tid];
        int x = v;
#pragma unroll
        for (int off = 1; off < 64; off <<= 1) {
            int t = __shfl_up(x, off);
            if (tid >= off) x += t;
        }
        int node = (b << 6) + tid;
        if (node < n) row_start[node] = base + x - v;
        cnt64[tid] = x - v;
    }
    __syncthreads();
    for (int j = tid; j < cnt; j += 256) {
        unsigned int pk = est[j];
        int pos = base + atomicAdd(&cnt64[pk >> 22], 1);
        edge_list[pos] = pk & 0x3FFFFFu;
    }
}

// ---------- per-node softmax + weighted aggregation; 1 wave = 1 node ----------
__global__ __launch_bounds__(256) void k_aggregate(
    const __half* __restrict__ zh, const float* __restrict__ s1, const float* __restrict__ s2,
    const float* __restrict__ rel_emb, const float* __restrict__ bias,
    const int* __restrict__ row_start, const unsigned int* __restrict__ edge_list,
    float* __restrict__ out, int n)
{
    __shared__ uint2 lds_ws[4][64];   // rare path only
    const int wv   = threadIdx.x >> 6;
    const int lane = threadIdx.x & 63;
    const int node = blockIdx.x * 4 + wv;
    if (node >= n) return;

    const int beg = row_start[node];
    const int end = row_start[node + 1];
    const int deg = end - beg;
    const int quad = lane >> 4;
    const int q    = lane & 15;

    float acc[8];
#pragma unroll
    for (int j = 0; j < 8; ++j) acc[j] = 0.f;
    const uint4* z4 = reinterpret_cast<const uint4*>(zh);

    if (deg > 0) {
        const float s2n = s2[node];

        if (deg <= 64) {
            unsigned int pk = 0;
            float ev = -3.4e38f;
            const bool has = lane < deg;
            if (has) {
                pk = edge_list[beg + lane];
                ev = s1[pk & 0xFFFFu] + s2n;
                ev = ev > 0.f ? ev : 0.01f * ev;
            }
            float m = ev;
#pragma unroll
            for (int off = 32; off > 0; off >>= 1)
                m = fmaxf(m, __shfl_xor(m, off));
            float p = has ? __expf(ev - m) : 0.f;
            float den = p;
#pragma unroll
            for (int off = 32; off > 0; off >>= 1)
                den += __shfl_xor(den, off);
            const float inv = 1.f / den;
            const int   src_i = has ? (int)(pk & 0xFFFFu) : 0;
            const float wgt   = has ? rel_emb[pk >> 16] * p * inv : 0.f;

            int jb = 0;
            for (; jb + 16 <= deg; jb += 16) {
                const int j0 = jb + quad;
                int   sA = __shfl(src_i, j0),      sB = __shfl(src_i, j0 + 4);
                int   sC = __shfl(src_i, j0 + 8),  sD = __shfl(src_i, j0 + 12);
                float wA = __shfl(wgt, j0),        wB = __shfl(wgt, j0 + 4);
                float wC = __shfl(wgt, j0 + 8),    wD = __shfl(wgt, j0 + 12);
                uint4 vA = z4[(size_t)sA * 16 + q];
                uint4 vB = z4[(size_t)sB * 16 + q];
                uint4 vC = z4[(size_t)sC * 16 + q];
                uint4 vD = z4[(size_t)sD * 16 + q];
                const __half* hA = reinterpret_cast<const __half*>(&vA);
                const __half* hB = reinterpret_cast<const __half*>(&vB);
                const __half* hC = reinterpret_cast<const __half*>(&vC);
                const __half* hD = reinterpret_cast<const __half*>(&vD);
#pragma unroll
                for (int k2 = 0; k2 < 8; ++k2) {
                    acc[k2] += wA * __half2float(hA[k2]);
                    acc[k2] += wB * __half2float(hB[k2]);
                    acc[k2] += wC * __half2float(hC[k2]);
                    acc[k2] += wD * __half2float(hD[k2]);
                }
            }
            for (; jb < deg; jb += 4) {
                const int j = jb + quad;
                int   sj = __shfl(src_i, j);
                float wj = __shfl(wgt, j);
                uint4 zv = z4[(size_t)sj * 16 + q];
                const __half* hp = reinterpret_cast<const __half*>(&zv);
#pragma unroll
                for (int k2 = 0; k2 < 8; ++k2)
                    acc[k2] += wj * __half2float(hp[k2]);
            }
        } else {
            float mymax = -3.4e38f;
            for (int k = beg + lane; k < end; k += 64) {
                unsigned int pk = edge_list[k];
                float ev = s1[pk & 0xFFFFu] + s2n;
                ev = ev > 0.f ? ev : 0.01f * ev;
                mymax = fmaxf(mymax, ev);
            }
#pragma unroll
            for (int off = 32; off > 0; off >>= 1)
                mymax = fmaxf(mymax, __shfl_xor(mymax, off));
            float mysum = 0.f;
            for (int k = beg + lane; k < end; k += 64) {
                unsigned int pk = edge_list[k];
                float ev = s1[pk & 0xFFFFu] + s2n;
                ev = ev > 0.f ? ev : 0.01f * ev;
                mysum += __expf(ev - mymax);
            }
#pragma unroll
            for (int off = 32; off > 0; off >>= 1)
                mysum += __shfl_xor(mysum, off);
            const float inv = 1.f / mysum;

            for (int cb = beg; cb < end; cb += 64) {
                int k = cb + lane;
                if (k < end) {
                    unsigned int pk = edge_list[k];
                    int s = pk & 0xFFFFu;
                    float ev = s1[s] + s2n;
                    ev = ev > 0.f ? ev : 0.01f * ev;
                    lds_ws[wv][lane] = make_uint2((unsigned)s,
                        __float_as_uint(rel_emb[pk >> 16] * __expf(ev - mymax) * inv));
                }
                int cnt = min(64, end - cb);
#pragma unroll 2
                for (int j = quad; j < cnt; j += 4) {
                    uint2 t = lds_ws[wv][j];
                    float w = __uint_as_float(t.y);
                    uint4 zv = z4[(size_t)t.x * 16 + q];
                    const __half* hp = reinterpret_cast<const __half*>(&zv);
#pragma unroll
                    for (int k2 = 0; k2 < 8; ++k2)
                        acc[k2] += w * __half2float(hp[k2]);
                }
            }
        }
#pragma unroll
        for (int j = 0; j < 8; ++j) {
            acc[j] += __shfl_xor(acc[j], 16);
            acc[j] += __shfl_xor(acc[j], 32);
        }
    }

    if (quad == 0) {
        const float4* b4 = reinterpret_cast<const float4*>(bias);
        float4 b0 = b4[q * 2], b1 = b4[q * 2 + 1];
        float4* o4 = reinterpret_cast<float4*>(out);
        o4[(size_t)node * 32 + q * 2] =
            make_float4(acc[0] + b0.x, acc[1] + b0.y, acc[2] + b0.z, acc[3] + b0.w);
        o4[(size_t)node * 32 + q * 2 + 1] =
            make_float4(acc[4] + b1.x, acc[5] + b1.y, acc[6] + b1.z, acc[7] + b1.w);
    }
}

extern "C" void kernel_launch(void* const* d_in, const int* in_sizes, int n_in,
                              void* d_out, int out_size, void* d_ws, size_t ws_size,
                              hipStream_t stream) {
    const float* h      = (const float*)d_in[0];
    const float* W      = (const float*)d_in[1];
    const float* attn_w = (const float*)d_in[2];
    const float* rel    = (const float*)d_in[3];
    const float* bias   = (const float*)d_in[4];
    const int*   src    = (const int*)d_in[5];
    const int*   dst    = (const int*)d_in[6];
    const int*   etype  = (const int*)d_in[7];
    const int n = in_sizes[0] / NFEAT;   // 50000
    const int e = in_sizes[5];           // 1600000
    const int nbuk = (n + 63) / 64;      // 782
    const int epb = (e + HB - 1) / HB;   // 6250
    float* out = (float*)d_out;

    // workspace layout
    char* p = (char*)d_ws;
    __half* zh = (__half*)p;               p += (size_t)n * NFEAT * 2;
    float* s1 = (float*)p;                 p += (size_t)n * 4;
    float* s2 = (float*)p;                 p += (size_t)n * 4;
    int* row_start = (int*)p;              p += (size_t)(n + 1) * 4;
    int* hist       = (int*)p;             p += (size_t)HB * nbuk * 4;
    int* base       = (int*)p;             p += (size_t)HB * nbuk * 4;
    int* bucket_tot = (int*)p;             p += (size_t)nbuk * 4;
    int* bucket_base= (int*)p;             p += (size_t)nbuk * 4;
    unsigned int* edge_list    = (unsigned int*)p;  p += (size_t)e * 4;
    unsigned int* bucket_store = (unsigned int*)p;  p += (size_t)e * 4;

    k_gemm_mfma<<<(n + 63) / 64, 256, 0, stream>>>(h, W, attn_w, zh, s1, s2, n);
    k_hist<<<HB, 256, 0, stream>>>(dst, hist, e, nbuk, epb);
    k_scan_blocks<<<nbuk, 256, 0, stream>>>(hist, base, bucket_tot, nbuk);
    k_scan_buckets<<<1, 256, 0, stream>>>(bucket_tot, bucket_base, row_start, n, nbuk);
    k_sctr<<<HB, 256, 0, stream>>>(src, dst, etype, base, bucket_base, bucket_store, e, nbuk, epb);
    k_place<<<nbuk, 256, 0, stream>>>(bucket_store, bucket_tot, bucket_base, row_start, edge_list, n);
    k_aggregate<<<(n + 3) / 4, 256, 0, stream>>>(zh, s1, s2, rel, bias, row_start, edge_list, out, n);
}

// Round 10
// 120.862 us; speedup vs baseline: 1.3025x; 1.0279x over previous
//
#include <hip/hip_runtime.h>
#include <hip/hip_fp16.h>

#define NFEAT 128
#define NBUK_MAX 1024   // actual buckets = ceil(50000/64) = 782
#define HB 256          // blocks for hist/scatter passes
#define EPB_MAX 6272    // LDS staging capacity per scatter block (epb = 6250)
#define HPAD 136        // padded LDS row stride in halves (272 B = 17 x 16 B)

typedef __attribute__((ext_vector_type(8))) _Float16 f16x8;
typedef __attribute__((ext_vector_type(4))) float f32x4;

// ---------- pass 1: per-block LDS histogram + W fp32->fp16 conversion ----------
__global__ __launch_bounds__(256) void k_hist(const int* __restrict__ dst,
                                              const float* __restrict__ W,
                                              _Float16* __restrict__ Wh,
                                              int* __restrict__ hist,
                                              int e, int nbuk, int epb)
{
    __shared__ int lh[NBUK_MAX];
    const int b = blockIdx.x, tid = threadIdx.x;
    // each block converts 64 elements of W (256 blocks x 64 = 16384)
    if (tid < 64) {
        int idx = b * 64 + tid;
        Wh[idx] = (_Float16)W[idx];
    }
    for (int k = tid; k < nbuk; k += 256) lh[k] = 0;
    __syncthreads();
    const int beg = b * epb, end = min(e, beg + epb);
    for (int i = beg + tid; i < end; i += 256)
        atomicAdd(&lh[dst[i] >> 6], 1);
    __syncthreads();
    for (int k = tid; k < nbuk; k += 256)
        hist[b * nbuk + k] = lh[k];
}

// ---------- MFMA gemm: z(fp16) = h @ W^T, s1 = z.w1, s2 = z.w2 ----------
__global__ __launch_bounds__(256) void k_gemm_mfma(
    const float* __restrict__ h, const _Float16* __restrict__ Wh,
    const float* __restrict__ attn_w,
    __half* __restrict__ zh, float* __restrict__ s1, float* __restrict__ s2, int n)
{
    __shared__ _Float16 hsh[64 * HPAD];    // h tile; later reused per-wave as z staging
    __shared__ _Float16 wsh[128 * HPAD];   // W (out x in) fp16
    const int tid = threadIdx.x;
    const int wv = tid >> 6, lane = tid & 63;
    const int nodeBase = blockIdx.x * 64;

    {   // stage Wh: 128x128 fp16 via 16B vector loads
        const uint4* Wv = reinterpret_cast<const uint4*>(Wh);
        for (int t = tid; t < 2048; t += 256) {
            int r = t >> 4, c8 = t & 15;
            *reinterpret_cast<uint4*>(&wsh[r * HPAD + c8 * 8]) = Wv[t];
        }
    }
    {   // stage h tile: 64x128 fp32 -> fp16
        const float4* h4 = reinterpret_cast<const float4*>(h);
        for (int t = tid; t < 64 * 32; t += 256) {
            int r = t >> 5, c4 = t & 31;
            int node = nodeBase + r;
            float4 v = (node < n) ? h4[(size_t)node * 32 + c4]
                                  : make_float4(0.f, 0.f, 0.f, 0.f);
            _Float16* d = &hsh[r * HPAD + c4 * 4];
            d[0] = (_Float16)v.x; d[1] = (_Float16)v.y;
            d[2] = (_Float16)v.z; d[3] = (_Float16)v.w;
        }
    }
    __syncthreads();

    const int arow = lane & 15;   // A-row / B-col
    const int kgrp = lane >> 4;   // k-group 0..3
    f32x4 acc[8];
#pragma unroll
    for (int t = 0; t < 8; ++t) acc[t] = (f32x4){0.f, 0.f, 0.f, 0.f};

#pragma unroll
    for (int k0 = 0; k0 < 128; k0 += 32) {
        f16x8 a = *reinterpret_cast<const f16x8*>(
            &hsh[(wv * 16 + arow) * HPAD + k0 + kgrp * 8]);
#pragma unroll
        for (int nt = 0; nt < 8; ++nt) {
            f16x8 b = *reinterpret_cast<const f16x8*>(
                &wsh[(nt * 16 + arow) * HPAD + k0 + kgrp * 8]);
            acc[nt] = __builtin_amdgcn_mfma_f32_16x16x32_f16(a, b, acc[nt], 0, 0, 0);
        }
    }

    // s1/s2 from fp32 accumulators: lane holds cols nt*16+arow, rows kgrp*4+r
    {
        float pr1[4] = {0.f, 0.f, 0.f, 0.f}, pr2[4] = {0.f, 0.f, 0.f, 0.f};
#pragma unroll
        for (int nt = 0; nt < 8; ++nt) {
            float w1v = attn_w[nt * 16 + arow];
            float w2v = attn_w[128 + nt * 16 + arow];
#pragma unroll
            for (int r = 0; r < 4; ++r) {
                pr1[r] += acc[nt][r] * w1v;
                pr2[r] += acc[nt][r] * w2v;
            }
        }
#pragma unroll
        for (int off = 1; off < 16; off <<= 1) {
#pragma unroll
            for (int r = 0; r < 4; ++r) {
                pr1[r] += __shfl_xor(pr1[r], off);
                pr2[r] += __shfl_xor(pr2[r], off);
            }
        }
        if (arow == 0) {
#pragma unroll
            for (int r = 0; r < 4; ++r) {
                int node = nodeBase + wv * 16 + kgrp * 4 + r;
                if (node < n) { s1[node] = pr1[r]; s2[node] = pr2[r]; }
            }
        }
    }

    _Float16* zout = &hsh[wv * 16 * HPAD];
#pragma unroll
    for (int nt = 0; nt < 8; ++nt)
#pragma unroll
        for (int r = 0; r < 4; ++r)
            zout[(kgrp * 4 + r) * HPAD + nt * 16 + arow] = (_Float16)acc[nt][r];

    {
        int node = nodeBase + wv * 16 + arow;
        if (node < n) {
            const uint4* zsrc = reinterpret_cast<const uint4*>(&zout[arow * HPAD + kgrp * 32]);
            uint4* zdst = reinterpret_cast<uint4*>(zh) + (size_t)node * 16 + kgrp * 4;
            uint4 v0 = zsrc[0], v1 = zsrc[1], v2 = zsrc[2], v3 = zsrc[3];
            zdst[0] = v0; zdst[1] = v1; zdst[2] = v2; zdst[3] = v3;
        }
    }
}

// ---------- pass 2: per-bucket exclusive scan over blocks ----------
__global__ __launch_bounds__(256) void k_scan_blocks(const int* __restrict__ hist,
                                                     int* __restrict__ base,
                                                     int* __restrict__ bucket_tot, int nbuk)
{
    __shared__ int wsum[4];
    const int k = blockIdx.x, tid = threadIdx.x;
    int v = hist[tid * nbuk + k];
    int lane = tid & 63, wave = tid >> 6;
    int x = v;
#pragma unroll
    for (int off = 1; off < 64; off <<= 1) {
        int t = __shfl_up(x, off);
        if (lane >= off) x += t;
    }
    if (lane == 63) wsum[wave] = x;
    __syncthreads();
    int wb = 0;
    for (int w = 0; w < wave; ++w) wb += wsum[w];
    base[tid * nbuk + k] = wb + x - v;
    if (tid == 255) bucket_tot[k] = wb + x;
}

// ---------- pass 3: LDS-staged dense scatter; computes bucket_base locally ----------
// packed word: (dst&63)<<22 | etype<<16 | src
__global__ __launch_bounds__(256) void k_sctr(
    const int* __restrict__ src, const int* __restrict__ dst, const int* __restrict__ etype,
    const int* __restrict__ base, const int* __restrict__ bucket_tot,
    int* __restrict__ bucket_base,
    unsigned int* __restrict__ bucket_store, int e, int nbuk, int epb)
{
    __shared__ unsigned int est[EPB_MAX];
    __shared__ unsigned short bkt[EPB_MAX];
    __shared__ int lcnt[NBUK_MAX];
    __shared__ int gbase[NBUK_MAX];   // first bb (bucket prefix), then final gbase
    __shared__ int lcur[NBUK_MAX];
    __shared__ int wsum[4];

    const int b = blockIdx.x, tid = threadIdx.x;
    const int beg = b * epb, end = min(e, beg + epb);
    const int cnt = end - beg;
    const int lane = tid & 63, wv = tid >> 6;
    const int C = (nbuk + 255) / 256;   // <= 4
    const int bi = tid * C;

    for (int k = tid; k < nbuk; k += 256) lcnt[k] = 0;

    // ---- scan 1: exclusive scan of bucket_tot -> gbase[] = bucket prefix (bb)
    {
        int vals[4];
        int s = 0;
#pragma unroll
        for (int j = 0; j < 4; ++j) {
            int v = 0;
            if (j < C) {
                int idx = bi + j;
                if (idx < nbuk) v = bucket_tot[idx];
            }
            vals[j] = v; s += v;
        }
        int x = s;
#pragma unroll
        for (int off = 1; off < 64; off <<= 1) {
            int t = __shfl_up(x, off);
            if (lane >= off) x += t;
        }
        if (lane == 63) wsum[wv] = x;
        __syncthreads();
        int wb = 0;
        for (int w = 0; w < wv; ++w) wb += wsum[w];
        int ex = wb + x - s;
#pragma unroll
        for (int j = 0; j < 4; ++j) {
            if (j < C) {
                int idx = bi + j;
                if (idx < nbuk) {
                    gbase[idx] = ex;
                    if (b == 0) bucket_base[idx] = ex;   // publish for k_place
                    ex += vals[j];
                }
            }
        }
    }
    __syncthreads();

    // ---- histogram this block's edges
    for (int i = beg + tid; i < end; i += 256)
        atomicAdd(&lcnt[dst[i] >> 6], 1);
    __syncthreads();

    // ---- scan 2: exclusive scan of lcnt; finalize gbase
    {
        int vals[4];
        int s = 0;
#pragma unroll
        for (int j = 0; j < 4; ++j) {
            int v = 0;
            if (j < C) {
                int idx = bi + j;
                if (idx < nbuk) v = lcnt[idx];
            }
            vals[j] = v; s += v;
        }
        int x = s;
#pragma unroll
        for (int off = 1; off < 64; off <<= 1) {
            int t = __shfl_up(x, off);
            if (lane >= off) x += t;
        }
        if (lane == 63) wsum[wv] = x;
        __syncthreads();
        int wb = 0;
        for (int w = 0; w < wv; ++w) wb += wsum[w];
        int ex = wb + x - s;
#pragma unroll
        for (int j = 0; j < 4; ++j) {
            if (j < C) {
                int idx = bi + j;
                if (idx < nbuk) {
                    lcur[idx] = ex;
                    gbase[idx] = gbase[idx] + base[b * nbuk + idx] - ex;
                    ex += vals[j];
                }
            }
        }
    }
    __syncthreads();

    // ---- scatter into LDS (bucket-sorted within block)
    for (int i = beg + tid; i < end; i += 256) {
        int d = dst[i];
        int k = d >> 6;
        unsigned int word =
            (unsigned int)src[i] | ((unsigned int)etype[i] << 16) | ((unsigned int)(d & 63) << 22);
        int pos = atomicAdd(&lcur[k], 1);
        est[pos] = word;
        bkt[pos] = (unsigned short)k;
    }
    __syncthreads();

    // ---- linear drain: dense runs at exact precomputed bases
    for (int j = tid; j < cnt; j += 256)
        bucket_store[gbase[bkt[j]] + j] = est[j];
}

// ---------- pass 4: per-bucket node sort -> CSR + row_start (no LDS staging) ----------
__global__ __launch_bounds__(256) void k_place(
    const unsigned int* __restrict__ bucket_store, const int* __restrict__ bucket_tot,
    const int* __restrict__ bucket_base,
    int* __restrict__ row_start, unsigned int* __restrict__ edge_list, int n)
{
    __shared__ int cnt64[64];
    const int b = blockIdx.x;
    const int tid = threadIdx.x;
    const int cnt = bucket_tot[b];
    const int base = bucket_base[b];

    if (tid < 64) cnt64[tid] = 0;
    __syncthreads();
    for (int j = tid; j < cnt; j += 256)
        atomicAdd(&cnt64[bucket_store[(size_t)base + j] >> 22], 1);
    __syncthreads();
    if (tid < 64) {
        int v = cnt64[tid];
        int x = v;
#pragma unroll
        for (int off = 1; off < 64; off <<= 1) {
            int t = __shfl_up(x, off);
            if (tid >= off) x += t;
        }
        int node = (b << 6) + tid;
        if (node < n) row_start[node] = base + x - v;
        cnt64[tid] = x - v;
    }
    if (tid == 0) {
        int bnd = (b << 6) + 64;
        if (bnd > n) bnd = n;
        row_start[bnd] = base + cnt;   // next bucket's base / row_start[n]
    }
    __syncthreads();
    for (int j = tid; j < cnt; j += 256) {
        unsigned int pk = bucket_store[(size_t)base + j];
        int pos = base + atomicAdd(&cnt64[pk >> 22], 1);
        edge_list[pos] = pk & 0x3FFFFFu;
    }
}

// ---------- per-node softmax + weighted aggregation; 1 wave = 1 node ----------
__global__ __launch_bounds__(256) void k_aggregate(
    const __half* __restrict__ zh, const float* __restrict__ s1, const float* __restrict__ s2,
    const float* __restrict__ rel_emb, const float* __restrict__ bias,
    const int* __restrict__ row_start, const unsigned int* __restrict__ edge_list,
    float* __restrict__ out, int n)
{
    __shared__ uint2 lds_ws[4][64];   // rare path only
    const int wv   = threadIdx.x >> 6;
    const int lane = threadIdx.x & 63;
    const int node = blockIdx.x * 4 + wv;
    if (node >= n) return;

    const int beg = row_start[node];
    const int end = row_start[node + 1];
    const int deg = end - beg;
    const int quad = lane >> 4;
    const int q    = lane & 15;

    float acc[8];
#pragma unroll
    for (int j = 0; j < 8; ++j) acc[j] = 0.f;
    const uint4* z4 = reinterpret_cast<const uint4*>(zh);

    if (deg > 0) {
        const float s2n = s2[node];

        if (deg <= 64) {
            unsigned int pk = 0;
            float ev = -3.4e38f;
            const bool has = lane < deg;
            if (has) {
                pk = edge_list[beg + lane];
                ev = s1[pk & 0xFFFFu] + s2n;
                ev = ev > 0.f ? ev : 0.01f * ev;
            }
            float m = ev;
#pragma unroll
            for (int off = 32; off > 0; off >>= 1)
                m = fmaxf(m, __shfl_xor(m, off));
            float p = has ? __expf(ev - m) : 0.f;
            float den = p;
#pragma unroll
            for (int off = 32; off > 0; off >>= 1)
                den += __shfl_xor(den, off);
            const float inv = 1.f / den;
            const int   src_i = has ? (int)(pk & 0xFFFFu) : 0;
            const float wgt   = has ? rel_emb[pk >> 16] * p * inv : 0.f;

            int jb = 0;
            for (; jb + 16 <= deg; jb += 16) {
                const int j0 = jb + quad;
                int   sA = __shfl(src_i, j0),      sB = __shfl(src_i, j0 + 4);
                int   sC = __shfl(src_i, j0 + 8),  sD = __shfl(src_i, j0 + 12);
                float wA = __shfl(wgt, j0),        wB = __shfl(wgt, j0 + 4);
                float wC = __shfl(wgt, j0 + 8),    wD = __shfl(wgt, j0 + 12);
                uint4 vA = z4[(size_t)sA * 16 + q];
                uint4 vB = z4[(size_t)sB * 16 + q];
                uint4 vC = z4[(size_t)sC * 16 + q];
                uint4 vD = z4[(size_t)sD * 16 + q];
                const __half* hA = reinterpret_cast<const __half*>(&vA);
                const __half* hB = reinterpret_cast<const __half*>(&vB);
                const __half* hC = reinterpret_cast<const __half*>(&vC);
                const __half* hD = reinterpret_cast<const __half*>(&vD);
#pragma unroll
                for (int k2 = 0; k2 < 8; ++k2) {
                    acc[k2] += wA * __half2float(hA[k2]);
                    acc[k2] += wB * __half2float(hB[k2]);
                    acc[k2] += wC * __half2float(hC[k2]);
                    acc[k2] += wD * __half2float(hD[k2]);
                }
            }
            for (; jb < deg; jb += 4) {
                const int j = jb + quad;
                int   sj = __shfl(src_i, j);
                float wj = __shfl(wgt, j);
                uint4 zv = z4[(size_t)sj * 16 + q];
                const __half* hp = reinterpret_cast<const __half*>(&zv);
#pragma unroll
                for (int k2 = 0; k2 < 8; ++k2)
                    acc[k2] += wj * __half2float(hp[k2]);
            }
        } else {
            float mymax = -3.4e38f;
            for (int k = beg + lane; k < end; k += 64) {
                unsigned int pk = edge_list[k];
                float ev = s1[pk & 0xFFFFu] + s2n;
                ev = ev > 0.f ? ev : 0.01f * ev;
                mymax = fmaxf(mymax, ev);
            }
#pragma unroll
            for (int off = 32; off > 0; off >>= 1)
                mymax = fmaxf(mymax, __shfl_xor(mymax, off));
            float mysum = 0.f;
            for (int k = beg + lane; k < end; k += 64) {
                unsigned int pk = edge_list[k];
                float ev = s1[pk & 0xFFFFu] + s2n;
                ev = ev > 0.f ? ev : 0.01f * ev;
                mysum += __expf(ev - mymax);
            }
#pragma unroll
            for (int off = 32; off > 0; off >>= 1)
                mysum += __shfl_xor(mysum, off);
            const float inv = 1.f / mysum;

            for (int cb = beg; cb < end; cb += 64) {
                int k = cb + lane;
                if (k < end) {
                    unsigned int pk = edge_list[k];
                    int s = pk & 0xFFFFu;
                    float ev = s1[s] + s2n;
                    ev = ev > 0.f ? ev : 0.01f * ev;
                    lds_ws[wv][lane] = make_uint2((unsigned)s,
                        __float_as_uint(rel_emb[pk >> 16] * __expf(ev - mymax) * inv));
                }
                int cnt = min(64, end - cb);
#pragma unroll 2
                for (int j = quad; j < cnt; j += 4) {
                    uint2 t = lds_ws[wv][j];
                    float w = __uint_as_float(t.y);
                    uint4 zv = z4[(size_t)t.x * 16 + q];
                    const __half* hp = reinterpret_cast<const __half*>(&zv);
#pragma unroll
                    for (int k2 = 0; k2 < 8; ++k2)
                        acc[k2] += w * __half2float(hp[k2]);
                }
            }
        }
#pragma unroll
        for (int j = 0; j < 8; ++j) {
            acc[j] += __shfl_xor(acc[j], 16);
            acc[j] += __shfl_xor(acc[j], 32);
        }
    }

    if (quad == 0) {
        const float4* b4 = reinterpret_cast<const float4*>(bias);
        float4 b0 = b4[q * 2], b1 = b4[q * 2 + 1];
        float4* o4 = reinterpret_cast<float4*>(out);
        o4[(size_t)node * 32 + q * 2] =
            make_float4(acc[0] + b0.x, acc[1] + b0.y, acc[2] + b0.z, acc[3] + b0.w);
        o4[(size_t)node * 32 + q * 2 + 1] =
            make_float4(acc[4] + b1.x, acc[5] + b1.y, acc[6] + b1.z, acc[7] + b1.w);
    }
}

extern "C" void kernel_launch(void* const* d_in, const int* in_sizes, int n_in,
                              void* d_out, int out_size, void* d_ws, size_t ws_size,
                              hipStream_t stream) {
    const float* h      = (const float*)d_in[0];
    const float* W      = (const float*)d_in[1];
    const float* attn_w = (const float*)d_in[2];
    const float* rel    = (const float*)d_in[3];
    const float* bias   = (const float*)d_in[4];
    const int*   src    = (const int*)d_in[5];
    const int*   dst    = (const int*)d_in[6];
    const int*   etype  = (const int*)d_in[7];
    const int n = in_sizes[0] / NFEAT;   // 50000
    const int e = in_sizes[5];           // 1600000
    const int nbuk = (n + 63) / 64;      // 782
    const int epb = (e + HB - 1) / HB;   // 6250
    float* out = (float*)d_out;

    // workspace layout
    char* p = (char*)d_ws;
    __half* zh = (__half*)p;               p += (size_t)n * NFEAT * 2;
    float* s1 = (float*)p;                 p += (size_t)n * 4;
    float* s2 = (float*)p;                 p += (size_t)n * 4;
    _Float16* Wh = (_Float16*)p;           p += (size_t)NFEAT * NFEAT * 2;
    int* row_start = (int*)p;              p += (size_t)(n + 1) * 4;
    int* hist       = (int*)p;             p += (size_t)HB * nbuk * 4;
    int* base       = (int*)p;             p += (size_t)HB * nbuk * 4;
    int* bucket_tot = (int*)p;             p += (size_t)nbuk * 4;
    int* bucket_base= (int*)p;             p += (size_t)nbuk * 4;
    unsigned int* edge_list    = (unsigned int*)p;  p += (size_t)e * 4;
    unsigned int* bucket_store = (unsigned int*)p;  p += (size_t)e * 4;

    k_hist<<<HB, 256, 0, stream>>>(dst, W, Wh, hist, e, nbuk, epb);
    k_gemm_mfma<<<(n + 63) / 64, 256, 0, stream>>>(h, Wh, attn_w, zh, s1, s2, n);
    k_scan_blocks<<<nbuk, 256, 0, stream>>>(hist, base, bucket_tot, nbuk);
    k_sctr<<<HB, 256, 0, stream>>>(src, dst, etype, base, bucket_tot, bucket_base,
                                   bucket_store, e, nbuk, epb);
    k_place<<<nbuk, 256, 0, stream>>>(bucket_store, bucket_tot, bucket_base,
                                      row_start, edge_list, n);
    k_aggregate<<<(n + 3) / 4, 256, 0, stream>>>(zh, s1, s2, rel, bias, row_start, edge_list, out, n);
}

// Round 11
// 118.245 us; speedup vs baseline: 1.3314x; 1.0221x over previous
//
#include <hip/hip_runtime.h>
#include <hip/hip_fp16.h>

#define NFEAT 128
#define NBUK_MAX 1024   // actual buckets = ceil(50000/64) = 782
#define HB 256          // blocks for hist/scatter passes
#define EPB_MAX 6272    // LDS staging capacity per scatter block (epb = 6250)
#define HPAD 136        // padded LDS row stride in halves (272 B = 17 x 16 B)

typedef __attribute__((ext_vector_type(8))) _Float16 f16x8;
typedef __attribute__((ext_vector_type(4))) float f32x4;

__device__ __forceinline__ uint4 ldz(const char* zb, int s, unsigned qoff) {
    return *reinterpret_cast<const uint4*>(zb + (((unsigned)s << 8) | qoff));
}
__device__ __forceinline__ void fma8(float* acc, const uint4& v, float w) {
    const __half* hp = reinterpret_cast<const __half*>(&v);
#pragma unroll
    for (int k2 = 0; k2 < 8; ++k2)
        acc[k2] = fmaf(w, __half2float(hp[k2]), acc[k2]);
}

// ---------- fused A: role-split blocks — MFMA gemm (782) + edge histogram (256) ----------
__global__ __launch_bounds__(256) void k_fused_a(
    const float* __restrict__ h, const float* __restrict__ W,
    const float* __restrict__ attn_w,
    __half* __restrict__ zh, float* __restrict__ s1, float* __restrict__ s2, int n,
    const int* __restrict__ dst, int* __restrict__ hist, int e, int nbuk, int epb,
    int gemmBlocks)
{
    __shared__ _Float16 smem[192 * HPAD];   // gemm: hsh(64)+wsh(128); hist: lh alias
    const int tid = threadIdx.x;

    if (blockIdx.x >= gemmBlocks) {
        // ---------------- histogram role ----------------
        int* lh = reinterpret_cast<int*>(smem);
        const int b = blockIdx.x - gemmBlocks;
        for (int k = tid; k < nbuk; k += 256) lh[k] = 0;
        __syncthreads();
        const int beg = b * epb, end = min(e, beg + epb);
        for (int i = beg + tid; i < end; i += 256)
            atomicAdd(&lh[dst[i] >> 6], 1);
        __syncthreads();
        for (int k = tid; k < nbuk; k += 256)
            hist[b * nbuk + k] = lh[k];
        return;
    }

    // ---------------- gemm role ----------------
    _Float16* hsh = smem;                  // [64 * HPAD]
    _Float16* wsh = smem + 64 * HPAD;      // [128 * HPAD]
    const int wv = tid >> 6, lane = tid & 63;
    const int nodeBase = blockIdx.x * 64;

    {   // stage W: 128x128 fp32 -> fp16
        const float4* W4 = reinterpret_cast<const float4*>(W);
        for (int t = tid; t < 128 * 32; t += 256) {
            int r = t >> 5, c4 = t & 31;
            float4 v = W4[t];
            _Float16* d = &wsh[r * HPAD + c4 * 4];
            d[0] = (_Float16)v.x; d[1] = (_Float16)v.y;
            d[2] = (_Float16)v.z; d[3] = (_Float16)v.w;
        }
    }
    {   // stage h tile: 64x128 fp32 -> fp16
        const float4* h4 = reinterpret_cast<const float4*>(h);
        for (int t = tid; t < 64 * 32; t += 256) {
            int r = t >> 5, c4 = t & 31;
            int node = nodeBase + r;
            float4 v = (node < n) ? h4[(size_t)node * 32 + c4]
                                  : make_float4(0.f, 0.f, 0.f, 0.f);
            _Float16* d = &hsh[r * HPAD + c4 * 4];
            d[0] = (_Float16)v.x; d[1] = (_Float16)v.y;
            d[2] = (_Float16)v.z; d[3] = (_Float16)v.w;
        }
    }
    __syncthreads();

    const int arow = lane & 15;   // A-row / B-col
    const int kgrp = lane >> 4;   // k-group 0..3
    f32x4 acc[8];
#pragma unroll
    for (int t = 0; t < 8; ++t) acc[t] = (f32x4){0.f, 0.f, 0.f, 0.f};

#pragma unroll
    for (int k0 = 0; k0 < 128; k0 += 32) {
        f16x8 a = *reinterpret_cast<const f16x8*>(
            &hsh[(wv * 16 + arow) * HPAD + k0 + kgrp * 8]);
#pragma unroll
        for (int nt = 0; nt < 8; ++nt) {
            f16x8 b = *reinterpret_cast<const f16x8*>(
                &wsh[(nt * 16 + arow) * HPAD + k0 + kgrp * 8]);
            acc[nt] = __builtin_amdgcn_mfma_f32_16x16x32_f16(a, b, acc[nt], 0, 0, 0);
        }
    }

    // s1/s2 from fp32 accumulators: lane holds cols nt*16+arow, rows kgrp*4+r
    {
        float pr1[4] = {0.f, 0.f, 0.f, 0.f}, pr2[4] = {0.f, 0.f, 0.f, 0.f};
#pragma unroll
        for (int nt = 0; nt < 8; ++nt) {
            float w1v = attn_w[nt * 16 + arow];
            float w2v = attn_w[128 + nt * 16 + arow];
#pragma unroll
            for (int r = 0; r < 4; ++r) {
                pr1[r] += acc[nt][r] * w1v;
                pr2[r] += acc[nt][r] * w2v;
            }
        }
#pragma unroll
        for (int off = 1; off < 16; off <<= 1) {
#pragma unroll
            for (int r = 0; r < 4; ++r) {
                pr1[r] += __shfl_xor(pr1[r], off);
                pr2[r] += __shfl_xor(pr2[r], off);
            }
        }
        if (arow == 0) {
#pragma unroll
            for (int r = 0; r < 4; ++r) {
                int node = nodeBase + wv * 16 + kgrp * 4 + r;
                if (node < n) { s1[node] = pr1[r]; s2[node] = pr2[r]; }
            }
        }
    }

    _Float16* zout = &hsh[wv * 16 * HPAD];
#pragma unroll
    for (int nt = 0; nt < 8; ++nt)
#pragma unroll
        for (int r = 0; r < 4; ++r)
            zout[(kgrp * 4 + r) * HPAD + nt * 16 + arow] = (_Float16)acc[nt][r];

    {
        int node = nodeBase + wv * 16 + arow;
        if (node < n) {
            const uint4* zsrc = reinterpret_cast<const uint4*>(&zout[arow * HPAD + kgrp * 32]);
            uint4* zdst = reinterpret_cast<uint4*>(zh) + (size_t)node * 16 + kgrp * 4;
            uint4 v0 = zsrc[0], v1 = zsrc[1], v2 = zsrc[2], v3 = zsrc[3];
            zdst[0] = v0; zdst[1] = v1; zdst[2] = v2; zdst[3] = v3;
        }
    }
}

// ---------- pass 2: per-bucket exclusive scan over blocks ----------
__global__ __launch_bounds__(256) void k_scan_blocks(const int* __restrict__ hist,
                                                     int* __restrict__ base,
                                                     int* __restrict__ bucket_tot, int nbuk)
{
    __shared__ int wsum[4];
    const int k = blockIdx.x, tid = threadIdx.x;
    int v = hist[tid * nbuk + k];
    int lane = tid & 63, wave = tid >> 6;
    int x = v;
#pragma unroll
    for (int off = 1; off < 64; off <<= 1) {
        int t = __shfl_up(x, off);
        if (lane >= off) x += t;
    }
    if (lane == 63) wsum[wave] = x;
    __syncthreads();
    int wb = 0;
    for (int w = 0; w < wave; ++w) wb += wsum[w];
    base[tid * nbuk + k] = wb + x - v;
    if (tid == 255) bucket_tot[k] = wb + x;
}

// ---------- pass 3: LDS-staged dense scatter; computes bucket_base locally ----------
// packed word: (dst&63)<<22 | etype<<16 | src
__global__ __launch_bounds__(256) void k_sctr(
    const int* __restrict__ src, const int* __restrict__ dst, const int* __restrict__ etype,
    const int* __restrict__ base, const int* __restrict__ bucket_tot,
    int* __restrict__ bucket_base,
    unsigned int* __restrict__ bucket_store, int e, int nbuk, int epb)
{
    __shared__ unsigned int est[EPB_MAX];
    __shared__ unsigned short bkt[EPB_MAX];
    __shared__ int lcnt[NBUK_MAX];
    __shared__ int gbase[NBUK_MAX];
    __shared__ int lcur[NBUK_MAX];
    __shared__ int wsum[4];

    const int b = blockIdx.x, tid = threadIdx.x;
    const int beg = b * epb, end = min(e, beg + epb);
    const int cnt = end - beg;
    const int lane = tid & 63, wv = tid >> 6;
    const int C = (nbuk + 255) / 256;   // <= 4
    const int bi = tid * C;

    for (int k = tid; k < nbuk; k += 256) lcnt[k] = 0;

    // scan 1: exclusive scan of bucket_tot -> bucket prefix
    {
        int vals[4];
        int s = 0;
#pragma unroll
        for (int j = 0; j < 4; ++j) {
            int v = 0;
            if (j < C) {
                int idx = bi + j;
                if (idx < nbuk) v = bucket_tot[idx];
            }
            vals[j] = v; s += v;
        }
        int x = s;
#pragma unroll
        for (int off = 1; off < 64; off <<= 1) {
            int t = __shfl_up(x, off);
            if (lane >= off) x += t;
        }
        if (lane == 63) wsum[wv] = x;
        __syncthreads();
        int wb = 0;
        for (int w = 0; w < wv; ++w) wb += wsum[w];
        int ex = wb + x - s;
#pragma unroll
        for (int j = 0; j < 4; ++j) {
            if (j < C) {
                int idx = bi + j;
                if (idx < nbuk) {
                    gbase[idx] = ex;
                    if (b == 0) bucket_base[idx] = ex;
                    ex += vals[j];
                }
            }
        }
    }
    __syncthreads();

    for (int i = beg + tid; i < end; i += 256)
        atomicAdd(&lcnt[dst[i] >> 6], 1);
    __syncthreads();

    // scan 2: exclusive scan of lcnt; finalize gbase
    {
        int vals[4];
        int s = 0;
#pragma unroll
        for (int j = 0; j < 4; ++j) {
            int v = 0;
            if (j < C) {
                int idx = bi + j;
                if (idx < nbuk) v = lcnt[idx];
            }
            vals[j] = v; s += v;
        }
        int x = s;
#pragma unroll
        for (int off = 1; off < 64; off <<= 1) {
            int t = __shfl_up(x, off);
            if (lane >= off) x += t;
        }
        if (lane == 63) wsum[wv] = x;
        __syncthreads();
        int wb = 0;
        for (int w = 0; w < wv; ++w) wb += wsum[w];
        int ex = wb + x - s;
#pragma unroll
        for (int j = 0; j < 4; ++j) {
            if (j < C) {
                int idx = bi + j;
                if (idx < nbuk) {
                    lcur[idx] = ex;
                    gbase[idx] = gbase[idx] + base[b * nbuk + idx] - ex;
                    ex += vals[j];
                }
            }
        }
    }
    __syncthreads();

    for (int i = beg + tid; i < end; i += 256) {
        int d = dst[i];
        int k = d >> 6;
        unsigned int word =
            (unsigned int)src[i] | ((unsigned int)etype[i] << 16) | ((unsigned int)(d & 63) << 22);
        int pos = atomicAdd(&lcur[k], 1);
        est[pos] = word;
        bkt[pos] = (unsigned short)k;
    }
    __syncthreads();

    for (int j = tid; j < cnt; j += 256)
        bucket_store[gbase[bkt[j]] + j] = est[j];
}

// ---------- pass 4: per-bucket node sort -> CSR + row_start ----------
__global__ __launch_bounds__(256) void k_place(
    const unsigned int* __restrict__ bucket_store, const int* __restrict__ bucket_tot,
    const int* __restrict__ bucket_base,
    int* __restrict__ row_start, unsigned int* __restrict__ edge_list, int n)
{
    __shared__ int cnt64[64];
    const int b = blockIdx.x;
    const int tid = threadIdx.x;
    const int cnt = bucket_tot[b];
    const int base = bucket_base[b];

    if (tid < 64) cnt64[tid] = 0;
    __syncthreads();
    for (int j = tid; j < cnt; j += 256)
        atomicAdd(&cnt64[bucket_store[(size_t)base + j] >> 22], 1);
    __syncthreads();
    if (tid < 64) {
        int v = cnt64[tid];
        int x = v;
#pragma unroll
        for (int off = 1; off < 64; off <<= 1) {
            int t = __shfl_up(x, off);
            if (tid >= off) x += t;
        }
        int node = (b << 6) + tid;
        if (node < n) row_start[node] = base + x - v;
        cnt64[tid] = x - v;
    }
    if (tid == 0) {
        int bnd = (b << 6) + 64;
        if (bnd > n) bnd = n;
        row_start[bnd] = base + cnt;
    }
    __syncthreads();
    for (int j = tid; j < cnt; j += 256) {
        unsigned int pk = bucket_store[(size_t)base + j];
        int pos = base + atomicAdd(&cnt64[pk >> 22], 1);
        edge_list[pos] = pk & 0x3FFFFFu;
    }
}

// ---------- per-node softmax + weighted aggregation; 1 wave = 1 node ----------
// fast path: software-pipelined 4+4 batches (8 z-loads in flight), 32-bit offsets.
__global__ __launch_bounds__(256) void k_aggregate(
    const __half* __restrict__ zh, const float* __restrict__ s1, const float* __restrict__ s2,
    const float* __restrict__ rel_emb, const float* __restrict__ bias,
    const int* __restrict__ row_start, const unsigned int* __restrict__ edge_list,
    float* __restrict__ out, int n)
{
    __shared__ uint2 lds_ws[4][64];   // rare path only
    const int wv   = threadIdx.x >> 6;
    const int lane = threadIdx.x & 63;
    const int node = blockIdx.x * 4 + wv;
    if (node >= n) return;

    const int beg = row_start[node];
    const int end = row_start[node + 1];
    const int deg = end - beg;
    const int quad = lane >> 4;
    const int q    = lane & 15;
    const unsigned qoff = (unsigned)q << 4;
    const char* zb = reinterpret_cast<const char*>(zh);

    float acc[8];
#pragma unroll
    for (int j = 0; j < 8; ++j) acc[j] = 0.f;

    if (deg > 0) {
        const float s2n = s2[node];

        if (deg <= 64) {
            unsigned int pk = 0;
            float ev = -3.4e38f;
            const bool has = lane < deg;
            if (has) {
                pk = edge_list[beg + lane];
                ev = s1[pk & 0xFFFFu] + s2n;
                ev = ev > 0.f ? ev : 0.01f * ev;
            }
            float m = ev;
#pragma unroll
            for (int off = 32; off > 0; off >>= 1)
                m = fmaxf(m, __shfl_xor(m, off));
            float p = has ? __expf(ev - m) : 0.f;
            float den = p;
#pragma unroll
            for (int off = 32; off > 0; off >>= 1)
                den += __shfl_xor(den, off);
            const float inv = 1.f / den;
            const int   src_i = has ? (int)(pk & 0xFFFFu) : 0;
            const float wgt   = has ? rel_emb[pk >> 16] * p * inv : 0.f;

            int jb = 0;
            if (deg >= 16) {
                // prologue: metadata + loads for batch 0
                int j0 = quad;
                int   sA = __shfl(src_i, j0),      sB = __shfl(src_i, j0 + 4);
                int   sC = __shfl(src_i, j0 + 8),  sD = __shfl(src_i, j0 + 12);
                float wA = __shfl(wgt, j0),        wB = __shfl(wgt, j0 + 4);
                float wC = __shfl(wgt, j0 + 8),    wD = __shfl(wgt, j0 + 12);
                uint4 vA = ldz(zb, sA, qoff), vB = ldz(zb, sB, qoff);
                uint4 vC = ldz(zb, sC, qoff), vD = ldz(zb, sD, qoff);
                for (; jb + 32 <= deg; jb += 16) {
                    int j1 = jb + 16 + quad;
                    int   tA = __shfl(src_i, j1),      tB = __shfl(src_i, j1 + 4);
                    int   tC = __shfl(src_i, j1 + 8),  tD = __shfl(src_i, j1 + 12);
                    float xA = __shfl(wgt, j1),        xB = __shfl(wgt, j1 + 4);
                    float xC = __shfl(wgt, j1 + 8),    xD = __shfl(wgt, j1 + 12);
                    uint4 uA = ldz(zb, tA, qoff), uB = ldz(zb, tB, qoff);
                    uint4 uC = ldz(zb, tC, qoff), uD = ldz(zb, tD, qoff);
                    fma8(acc, vA, wA); fma8(acc, vB, wB);
                    fma8(acc, vC, wC); fma8(acc, vD, wD);
                    vA = uA; vB = uB; vC = uC; vD = uD;
                    wA = xA; wB = xB; wC = xC; wD = xD;
                }
                fma8(acc, vA, wA); fma8(acc, vB, wB);
                fma8(acc, vC, wC); fma8(acc, vD, wD);
                jb += 16;
            }
            for (; jb < deg; jb += 4) {
                const int j = jb + quad;   // j < 64 always; wgt=0 beyond deg
                int   sj = __shfl(src_i, j);
                float wj = __shfl(wgt, j);
                uint4 zv = ldz(zb, sj, qoff);
                fma8(acc, zv, wj);
            }
        } else {
            // ---- rare path: degree > 64, chunked via LDS
            float mymax = -3.4e38f;
            for (int k = beg + lane; k < end; k += 64) {
                unsigned int pk = edge_list[k];
                float ev = s1[pk & 0xFFFFu] + s2n;
                ev = ev > 0.f ? ev : 0.01f * ev;
                mymax = fmaxf(mymax, ev);
            }
#pragma unroll
            for (int off = 32; off > 0; off >>= 1)
                mymax = fmaxf(mymax, __shfl_xor(mymax, off));
            float mysum = 0.f;
            for (int k = beg + lane; k < end; k += 64) {
                unsigned int pk = edge_list[k];
                float ev = s1[pk & 0xFFFFu] + s2n;
                ev = ev > 0.f ? ev : 0.01f * ev;
                mysum += __expf(ev - mymax);
            }
#pragma unroll
            for (int off = 32; off > 0; off >>= 1)
                mysum += __shfl_xor(mysum, off);
            const float inv = 1.f / mysum;

            for (int cb = beg; cb < end; cb += 64) {
                int k = cb + lane;
                if (k < end) {
                    unsigned int pk = edge_list[k];
                    int s = pk & 0xFFFFu;
                    float ev = s1[s] + s2n;
                    ev = ev > 0.f ? ev : 0.01f * ev;
                    lds_ws[wv][lane] = make_uint2((unsigned)s,
                        __float_as_uint(rel_emb[pk >> 16] * __expf(ev - mymax) * inv));
                }
                int cnt = min(64, end - cb);
#pragma unroll 2
                for (int j = quad; j < cnt; j += 4) {
                    uint2 t = lds_ws[wv][j];
                    float w = __uint_as_float(t.y);
                    uint4 zv = ldz(zb, (int)t.x, qoff);
                    fma8(acc, zv, w);
                }
            }
        }
#pragma unroll
        for (int j = 0; j < 8; ++j) {
            acc[j] += __shfl_xor(acc[j], 16);
            acc[j] += __shfl_xor(acc[j], 32);
        }
    }

    if (quad == 0) {
        const float4* b4 = reinterpret_cast<const float4*>(bias);
        float4 b0 = b4[q * 2], b1 = b4[q * 2 + 1];
        float4* o4 = reinterpret_cast<float4*>(out);
        o4[(size_t)node * 32 + q * 2] =
            make_float4(acc[0] + b0.x, acc[1] + b0.y, acc[2] + b0.z, acc[3] + b0.w);
        o4[(size_t)node * 32 + q * 2 + 1] =
            make_float4(acc[4] + b1.x, acc[5] + b1.y, acc[6] + b1.z, acc[7] + b1.w);
    }
}

extern "C" void kernel_launch(void* const* d_in, const int* in_sizes, int n_in,
                              void* d_out, int out_size, void* d_ws, size_t ws_size,
                              hipStream_t stream) {
    const float* h      = (const float*)d_in[0];
    const float* W      = (const float*)d_in[1];
    const float* attn_w = (const float*)d_in[2];
    const float* rel    = (const float*)d_in[3];
    const float* bias   = (const float*)d_in[4];
    const int*   src    = (const int*)d_in[5];
    const int*   dst    = (const int*)d_in[6];
    const int*   etype  = (const int*)d_in[7];
    const int n = in_sizes[0] / NFEAT;   // 50000
    const int e = in_sizes[5];           // 1600000
    const int nbuk = (n + 63) / 64;      // 782
    const int epb = (e + HB - 1) / HB;   // 6250
    const int gemmBlocks = (n + 63) / 64;
    float* out = (float*)d_out;

    // workspace layout
    char* p = (char*)d_ws;
    __half* zh = (__half*)p;               p += (size_t)n * NFEAT * 2;
    float* s1 = (float*)p;                 p += (size_t)n * 4;
    float* s2 = (float*)p;                 p += (size_t)n * 4;
    int* row_start = (int*)p;              p += (size_t)(n + 1) * 4;
    int* hist       = (int*)p;             p += (size_t)HB * nbuk * 4;
    int* base       = (int*)p;             p += (size_t)HB * nbuk * 4;
    int* bucket_tot = (int*)p;             p += (size_t)nbuk * 4;
    int* bucket_base= (int*)p;             p += (size_t)nbuk * 4;
    unsigned int* edge_list    = (unsigned int*)p;  p += (size_t)e * 4;
    unsigned int* bucket_store = (unsigned int*)p;  p += (size_t)e * 4;

    k_fused_a<<<gemmBlocks + HB, 256, 0, stream>>>(h, W, attn_w, zh, s1, s2, n,
                                                   dst, hist, e, nbuk, epb, gemmBlocks);
    k_scan_blocks<<<nbuk, 256, 0, stream>>>(hist, base, bucket_tot, nbuk);
    k_sctr<<<HB, 256, 0, stream>>>(src, dst, etype, base, bucket_tot, bucket_base,
                                   bucket_store, e, nbuk, epb);
    k_place<<<nbuk, 256, 0, stream>>>(bucket_store, bucket_tot, bucket_base,
                                      row_start, edge_list, n);
    k_aggregate<<<(n + 3) / 4, 256, 0, stream>>>(zh, s1, s2, rel, bias, row_start, edge_list, out, n);
}